// Round 10
// baseline (356.946 us; speedup 1.0000x reference)
//
#include <hip/hip_runtime.h>
#include <cstddef>

constexpr int Bn = 16, Kn = 256, Rn = 256, Tn = 1000, C8 = 8, SW = 16;
constexpr size_t UP_SZ    = (size_t)Bn * Tn * Rn;          // 4,096,000
constexpr size_t MASK_OFF = UP_SZ;                          // + 16,000
constexpr size_t LEN_OFF  = MASK_OFF + (size_t)Bn * Tn;     // + 16
constexpr size_t W_OFF    = LEN_OFF + Bn;                    // + 4,096,000

using half4_t = __attribute__((ext_vector_type(4))) _Float16;
using f32x4_t = __attribute__((ext_vector_type(4))) float;
using uint2_t = __attribute__((ext_vector_type(2))) unsigned int;

__device__ __forceinline__ float fast_rcp(float x) { return __builtin_amdgcn_rcpf(x); }
__device__ __forceinline__ float fast_exp2(float x) { return __builtin_amdgcn_exp2f(x); }
constexpr float LOG2E = 1.44269504088896340736f;
__device__ __forceinline__ float silu_f(float x) {
    return x * fast_rcp(1.f + fast_exp2(-LOG2E * x));
}

// pack 4 floats -> fp16 hi + lo halves
__device__ __forceinline__ void split4(const float x0, const float x1,
                                       const float x2, const float x3,
                                       half4_t& hi, half4_t& lo)
{
    const auto h01 = __builtin_amdgcn_cvt_pkrtz(x0, x1);
    const auto h23 = __builtin_amdgcn_cvt_pkrtz(x2, x3);
    uint2_t uh; uh.x = __builtin_bit_cast(unsigned int, h01);
    uh.y = __builtin_bit_cast(unsigned int, h23);
    hi = __builtin_bit_cast(half4_t, uh);
    const auto l01 = __builtin_amdgcn_cvt_pkrtz(x0 - (float)h01.x, x1 - (float)h01.y);
    const auto l23 = __builtin_amdgcn_cvt_pkrtz(x2 - (float)h23.x, x3 - (float)h23.y);
    uint2_t ul; ul.x = __builtin_bit_cast(unsigned int, l01);
    ul.y = __builtin_bit_cast(unsigned int, l23);
    lo = __builtin_bit_cast(half4_t, ul);
}

// ---------------- conv phase A: partial sums over r-chunks ----------------
__global__ __launch_bounds__(256) void conv_partial_kernel(
    const float* __restrict__ V,
    const float* __restrict__ wW, const float* __restrict__ wC,
    float* __restrict__ part)
{
    const int rc = blockIdx.x, b = blockIdx.y, k = threadIdx.x;
    constexpr int RPAD = 33;
    __shared__ float vt[258 * RPAD];
    if (k < 16) {
        const int row = (k < 8) ? 0 : 257;
        const int j = (k & 7) * 4;
        vt[row * RPAD + j] = 0.f; vt[row * RPAD + j + 1] = 0.f;
        vt[row * RPAD + j + 2] = 0.f; vt[row * RPAD + j + 3] = 0.f;
    }
    const float* vsrc = V + ((size_t)(b * Kn + k)) * Rn + rc * 32;
#pragma unroll
    for (int j = 0; j < 8; j++) {
        const float4 qv = *(const float4*)(vsrc + j * 4);
        float* dst = &vt[(k + 1) * RPAD + j * 4];
        dst[0] = qv.x; dst[1] = qv.y; dst[2] = qv.z; dst[3] = qv.w;
    }
    __syncthreads();

    float aw[C8], ac[C8];
#pragma unroll
    for (int c = 0; c < C8; c++) { aw[c] = 0.f; ac[c] = 0.f; }
    for (int dk = 0; dk < 3; dk++) {
        const float* wp = wW + (size_t)(dk * Rn + rc * 32) * C8;
        const float* cp = wC + (size_t)(dk * Rn + rc * 32) * C8;
        const float* vrow = &vt[(k + dk) * RPAD];
#pragma unroll 4
        for (int r = 0; r < 32; r++) {
            const float v = vrow[r];
#pragma unroll
            for (int c = 0; c < C8; c++) {
                aw[c] = fmaf(v, wp[r * C8 + c], aw[c]);
                ac[c] = fmaf(v, cp[r * C8 + c], ac[c]);
            }
        }
    }
    float* dst = part + ((size_t)(b * 8 + rc) * Kn + k) * 16;
    *(float4*)(dst + 0)  = make_float4(aw[0], aw[1], aw[2], aw[3]);
    *(float4*)(dst + 4)  = make_float4(aw[4], aw[5], aw[6], aw[7]);
    *(float4*)(dst + 8)  = make_float4(ac[0], ac[1], ac[2], ac[3]);
    *(float4*)(dst + 12) = make_float4(ac[4], ac[5], ac[6], ac[7]);
}

// ---------------- conv phase B (fused with scan): reduce + post + beta/alpha ----------------
__device__ __forceinline__ void conv_post(
    const float* acc, const float* cb, const float* bng, const float* bnb,
    const float* lng, const float* lnb, const float* w1, const float* b1,
    float* __restrict__ dst)
{
    const float bnscale = rsqrtf(1.f + 1e-5f);
    float x[C8];
    float mu = 0.f;
#pragma unroll
    for (int c = 0; c < C8; c++) {
        float v = (acc[c] + cb[c]) * (bng[c] * bnscale) + bnb[c];
        v = silu_f(v);
        x[c] = v; mu += v;
    }
    mu *= (1.f / C8);
    float var = 0.f;
#pragma unroll
    for (int c = 0; c < C8; c++) { float dd = x[c] - mu; var += dd * dd; }
    var *= (1.f / C8);
    const float rs = rsqrtf(var + 1e-5f);
    float y[C8];
#pragma unroll
    for (int c = 0; c < C8; c++) y[c] = (x[c] - mu) * rs * lng[c] + lnb[c];
#pragma unroll
    for (int c2 = 0; c2 < SW; c2++) {
        float a = b1[c2];
#pragma unroll
        for (int p = 0; p < C8; p++) a = fmaf(y[p], w1[(2 + p) * SW + c2], a);
        dst[c2] = a;
    }
}

__global__ __launch_bounds__(256) void conv_scan_finish_kernel(
    const float* __restrict__ dur,
    const float* __restrict__ part,
    const unsigned char* __restrict__ tmask_g,
    const float* __restrict__ bW, const float* __restrict__ bngW, const float* __restrict__ bnbW,
    const float* __restrict__ lngW, const float* __restrict__ lnbW,
    const float* __restrict__ bC, const float* __restrict__ bngC, const float* __restrict__ bnbC,
    const float* __restrict__ lngC, const float* __restrict__ lnbC,
    const float* __restrict__ sww_w1, const float* __restrict__ sww_b1,
    const float* __restrict__ swc_w1, const float* __restrict__ swc_b1,
    float* __restrict__ alpha_ws, float* __restrict__ ab_ws,
    int* __restrict__ len_ws, float* __restrict__ out)
{
    const int b = blockIdx.x, k = threadIdx.x;
    __shared__ float sc[Kn];
    const float d = dur[b * Kn + k];
    sc[k] = d;
    __syncthreads();
    for (int off = 1; off < Kn; off <<= 1) {
        float v = (k >= off) ? sc[k - off] : 0.f;
        __syncthreads();
        sc[k] += v;
        __syncthreads();
    }
    const float ek = sc[k];
    const float sk = ek - d;
    const float total = sc[Kn - 1];
    int len = (int)rintf(total);
    if (len > Tn) len = Tn;
    if (k == 0) { len_ws[b] = len; out[LEN_OFF + b] = (float)len; }
    for (int t = k; t < Tn; t += 256)
        out[MASK_OFF + (size_t)b * Tn + t] = (t >= len) ? 1.f : 0.f;
    if (b == 0 && k < 16) {
        alpha_ws[k]      = sww_w1[k] - sww_w1[SW + k];
        alpha_ws[16 + k] = swc_w1[k] - swc_w1[SW + k];
    }

    float aw[C8], ac[C8];
#pragma unroll
    for (int c = 0; c < C8; c++) { aw[c] = 0.f; ac[c] = 0.f; }
#pragma unroll 2
    for (int rc = 0; rc < 8; rc++) {
        const float4* p = (const float4*)(part + ((size_t)(b * 8 + rc) * Kn + k) * 16);
        const float4 q0 = p[0], q1 = p[1], q2 = p[2], q3 = p[3];
        aw[0] += q0.x; aw[1] += q0.y; aw[2] += q0.z; aw[3] += q0.w;
        aw[4] += q1.x; aw[5] += q1.y; aw[6] += q1.z; aw[7] += q1.w;
        ac[0] += q2.x; ac[1] += q2.y; ac[2] += q2.z; ac[3] += q2.w;
        ac[4] += q3.x; ac[5] += q3.y; ac[6] += q3.z; ac[7] += q3.w;
    }
    float basew[SW], basec[SW];
    conv_post(aw, bW, bngW, bnbW, lngW, lnbW, sww_w1, sww_b1, basew);
    conv_post(ac, bC, bngC, bnbC, lngC, lnbC, swc_w1, swc_b1, basec);

    const bool msk = tmask_g[b * Kn + k] != 0;
    // transposed layout: ab_ws[b*8192 + c*256 + k]  (c 0..15 = W-beta, 16..31 = C-beta)
    float* dstb = ab_ws + (size_t)b * 8192;
#pragma unroll
    for (int c = 0; c < SW; c++) {
        const float w0w = sww_w1[c], w1w_ = sww_w1[SW + c];
        const float w0c = swc_w1[c], w1c_ = swc_w1[SW + c];
        dstb[c * 256 + k]        = msk ? basew[c] : fmaf(ek, w1w_, fmaf(-sk, w0w, basew[c]));
        dstb[(16 + c) * 256 + k] = msk ? basec[c] : fmaf(ek, w1c_, fmaf(-sk, w0c, basec[c]));
    }
}

// ---------- C1: wave-per-t logits: swish blocks via MFMA + in-wave softmax, NO barriers ----------
__global__ __launch_bounds__(256) void logits_kernel(
    const unsigned char* __restrict__ tm, const int* __restrict__ len_ws,
    const float* __restrict__ alpha_ws, const float* __restrict__ ab_ws,
    const float* __restrict__ sww_w2, const float* __restrict__ sww_b2,
    const float* __restrict__ proj_w, const float* __restrict__ proj_b,
    const float* __restrict__ swc_w2, const float* __restrict__ swc_b2,
    float* __restrict__ agg_ws, float* __restrict__ out)
{
    const int t0 = blockIdx.x * 16, b = blockIdx.y, tid = threadIdx.x;
    const int lane = tid & 63, w = tid >> 6, q = lane >> 4, m = lane & 15;
    const int len = len_ws[b];

    // per-wave private buffers: 64 rows x 10 u32 (hi, lo); hc reuses hi after softmax
    __shared__ __align__(16) unsigned int BUF[4][2][648];
    unsigned int* hi_buf = &BUF[w][0][0];
    unsigned int* lo_buf = &BUF[w][1][0];

    // uniform A-fragments
    half4_t AWhi, AWlo, ACf;
    float pj[4], b2wv[4], b2cv[4];
#pragma unroll
    for (int i = 0; i < 4; i++) {
        const int c = 4 * q + i;
        const float vw = sww_w2[c * SW + m];
        const _Float16 hif = (_Float16)vw;
        AWhi[i] = hif;
        AWlo[i] = (_Float16)(vw - (float)hif);
        ACf[i]  = (_Float16)(swc_w2[c * SW + m]);
        pj[i]   = proj_w[c];
        b2wv[i] = sww_b2[c];
        b2cv[i] = swc_b2[c];
    }
    const float pb = proj_b[0];

    float aW[16], aC[16];
#pragma unroll
    for (int c = 0; c < 16; c++) { aW[c] = alpha_ws[c]; aC[c] = alpha_ws[16 + c]; }
    float mbv[16];
#pragma unroll
    for (int j = 0; j < 16; j++)
        mbv[j] = (tm[b * Kn + 16 * j + m] != 0) ? -INFINITY : 0.f;
    float mk4[4];
#pragma unroll
    for (int g = 0; g < 4; g++)
        mk4[g] = (tm[b * Kn + 64 * g + lane] != 0) ? 0.f : 1.f;

    const float* abW = ab_ws + (size_t)b * 8192;
    const float* abC = abW + 4096;

    for (int s = 0; s < 4; s++) {
        const int t = t0 + 4 * w + s;
        if (t >= len) {                          // wave-uniform; no barriers -> safe divergence
            if (t < Tn) {
                float* __restrict__ W_out = out + W_OFF + ((size_t)b * Tn + t) * Kn;
#pragma unroll
                for (int jj = 0; jj < 4; jj++)
                    W_out[16 * (4 * q + jj) + m] = 0.f;
            }
            continue;
        }
        float* __restrict__ W_out = out + W_OFF + ((size_t)b * Tn + t) * Kn;
        const float u = (float)(t + 1);

        float lg[16];
        // ---- phase 1: W-path layer-1 + split-fp16 MFMA + logits, group by group ----
#pragma unroll
        for (int g = 0; g < 4; g++) {
            const int k = 64 * g + lane;
            const float umk = u * mk4[g];
            unsigned int hp8[8], lp8[8];
#pragma unroll
            for (int p = 0; p < 8; p++) {
                const float x0 = fmaf(umk, aW[2 * p],     abW[(2 * p) * 256 + k]);
                const float x1 = fmaf(umk, aW[2 * p + 1], abW[(2 * p + 1) * 256 + k]);
                const float h0 = silu_f(x0), h1 = silu_f(x1);
                const auto hp = __builtin_amdgcn_cvt_pkrtz(h0, h1);
                hp8[p] = __builtin_bit_cast(unsigned int, hp);
                lp8[p] = __builtin_bit_cast(unsigned int,
                          __builtin_amdgcn_cvt_pkrtz(h0 - (float)hp.x, h1 - (float)hp.y));
            }
#pragma unroll
            for (int p = 0; p < 4; p++) {
                uint2_t a; a.x = hp8[2 * p]; a.y = hp8[2 * p + 1];
                *(uint2_t*)&hi_buf[lane * 10 + 2 * p] = a;
                uint2_t bb; bb.x = lp8[2 * p]; bb.y = lp8[2 * p + 1];
                *(uint2_t*)&lo_buf[lane * 10 + 2 * p] = bb;
            }
            // in-wave DS ordering: this wave's reads see its own writes
#pragma unroll
            for (int jj = 0; jj < 4; jj++) {
                const int row = 16 * jj + m;
                const half4_t bh = __builtin_bit_cast(half4_t, *(const uint2_t*)&hi_buf[row * 10 + 2 * q]);
                const half4_t bl = __builtin_bit_cast(half4_t, *(const uint2_t*)&lo_buf[row * 10 + 2 * q]);
                f32x4_t o = {0.f, 0.f, 0.f, 0.f};
                o = __builtin_amdgcn_mfma_f32_16x16x16f16(AWlo, bh, o, 0, 0, 0);
                o = __builtin_amdgcn_mfma_f32_16x16x16f16(AWhi, bl, o, 0, 0, 0);
                o = __builtin_amdgcn_mfma_f32_16x16x16f16(AWhi, bh, o, 0, 0, 0);
                float ss = silu_f(o[0] + b2wv[0]) * pj[0];
                ss = fmaf(silu_f(o[1] + b2wv[1]), pj[1], ss);
                ss = fmaf(silu_f(o[2] + b2wv[2]), pj[2], ss);
                ss = fmaf(silu_f(o[3] + b2wv[3]), pj[3], ss);
                ss += __shfl_xor(ss, 16, 64);
                ss += __shfl_xor(ss, 32, 64);
                lg[4 * g + jj] = ss + pb + mbv[4 * g + jj];
            }
        }

        // ---- in-wave softmax over 256 rows ----
        float M = lg[0];
#pragma unroll
        for (int j = 1; j < 16; j++) M = fmaxf(M, lg[j]);
#pragma unroll
        for (int off = 1; off <= 8; off <<= 1) M = fmaxf(M, __shfl_xor(M, off, 64));
        float wgt[16];
        float ssum = 0.f;
#pragma unroll
        for (int j = 0; j < 16; j++) {
            wgt[j] = fast_exp2(LOG2E * (lg[j] - M));
            ssum += wgt[j];
        }
#pragma unroll
        for (int off = 1; off <= 8; off <<= 1) ssum += __shfl_xor(ssum, off, 64);
        const float inv = fast_rcp(ssum);
#pragma unroll
        for (int j = 0; j < 16; j++) wgt[j] *= inv;

        // ---- W output (avoid runtime-indexed regs: cndmask select) ----
#pragma unroll
        for (int jj = 0; jj < 4; jj++) {
            float v = wgt[jj];
            v = (q == 1) ? wgt[4 + jj]  : v;
            v = (q == 2) ? wgt[8 + jj]  : v;
            v = (q == 3) ? wgt[12 + jj] : v;
            W_out[16 * (4 * q + jj) + m] = v;
        }

        // ---- phase 2: C-path (fp16) + weighted agg; hc reuses hi_buf ----
        f32x4_t ap = {0.f, 0.f, 0.f, 0.f};
#pragma unroll
        for (int g = 0; g < 4; g++) {
            const int k = 64 * g + lane;
            const float umk = u * mk4[g];
            unsigned int cp8[8];
#pragma unroll
            for (int p = 0; p < 8; p++) {
                const float y0 = fmaf(umk, aC[2 * p],     abC[(2 * p) * 256 + k]);
                const float y1 = fmaf(umk, aC[2 * p + 1], abC[(2 * p + 1) * 256 + k]);
                cp8[p] = __builtin_bit_cast(unsigned int,
                          __builtin_amdgcn_cvt_pkrtz(silu_f(y0), silu_f(y1)));
            }
#pragma unroll
            for (int p = 0; p < 4; p++) {
                uint2_t a; a.x = cp8[2 * p]; a.y = cp8[2 * p + 1];
                *(uint2_t*)&hi_buf[lane * 10 + 2 * p] = a;
            }
#pragma unroll
            for (int jj = 0; jj < 4; jj++) {
                const int row = 16 * jj + m;
                const half4_t bc = __builtin_bit_cast(half4_t, *(const uint2_t*)&hi_buf[row * 10 + 2 * q]);
                f32x4_t zz = {0.f, 0.f, 0.f, 0.f};
                const f32x4_t oc = __builtin_amdgcn_mfma_f32_16x16x16f16(ACf, bc, zz, 0, 0, 0);
#pragma unroll
                for (int i = 0; i < 4; i++)
                    ap[i] = fmaf(silu_f(oc[i] + b2cv[i]), wgt[4 * g + jj], ap[i]);
            }
        }
#pragma unroll
        for (int off = 1; off <= 8; off <<= 1) {
            ap[0] += __shfl_xor(ap[0], off, 64);
            ap[1] += __shfl_xor(ap[1], off, 64);
            ap[2] += __shfl_xor(ap[2], off, 64);
            ap[3] += __shfl_xor(ap[3], off, 64);
        }
        if (m == 0)
            *(float4*)&agg_ws[((size_t)b * Tn + t) * 16 + 4 * q] =
                make_float4(ap[0], ap[1], ap[2], ap[3]);
    }
}

// ---------------- C2: raw = W@V via MFMA, B-frags straight from V (coalesced) ----------------
__global__ __launch_bounds__(256) void matvec_mfma_kernel(
    const float* __restrict__ Wg, const float* __restrict__ V,
    float* __restrict__ out)
{
    const int tb = blockIdx.x, rq = blockIdx.y, b = blockIdx.z;
    const int t0 = tb * 32, r0 = rq * 64;
    const int tid = threadIdx.x;
    const int lane = tid & 63, w = tid >> 6, q = lane >> 4, m = lane & 15;
    __shared__ float4 Wl[32 * 64];   // 32 KiB, XOR-swizzled slots

    const float4* Wg4 = (const float4*)Wg;
#pragma unroll
    for (int ch = 0; ch < 8; ch++) {
        const int idx = ch * 256 + tid;
        const int row = idx >> 6, sl = idx & 63;
        const int t = t0 + row;
        const float4 v = (t < Tn) ? Wg4[((size_t)b * Tn + t) * 64 + sl]
                                  : make_float4(0.f, 0.f, 0.f, 0.f);
        Wl[row * 64 + (sl ^ (row & 7))] = v;
    }
    __syncthreads();

    const int tt = w & 1;
    const int rp = w >> 1;
    const int wrow = tt * 16 + m;
    const int rcol = r0 + rp * 32 + m;
    const float* Vb = V + (size_t)b * Kn * Rn;

    f32x4_t acc0 = {0.f, 0.f, 0.f, 0.f};
    f32x4_t acc1 = {0.f, 0.f, 0.f, 0.f};

#pragma unroll
    for (int ks = 0; ks < 16; ks++) {
        const float4 wv = Wl[wrow * 64 + ((ks * 4 + q) ^ (wrow & 7))];
        half4_t Ahi, Alo;
        split4(wv.x, wv.y, wv.z, wv.w, Ahi, Alo);

        const float* vp = Vb + (size_t)(ks * 16 + 4 * q) * Rn;
        const float b00 = vp[rcol],          b01 = vp[Rn + rcol];
        const float b02 = vp[2 * Rn + rcol], b03 = vp[3 * Rn + rcol];
        const float b10 = vp[rcol + 16],          b11 = vp[Rn + rcol + 16];
        const float b12 = vp[2 * Rn + rcol + 16], b13 = vp[3 * Rn + rcol + 16];
        half4_t Bh0, Bl0, Bh1, Bl1;
        split4(b00, b01, b02, b03, Bh0, Bl0);
        split4(b10, b11, b12, b13, Bh1, Bl1);

        acc0 = __builtin_amdgcn_mfma_f32_16x16x16f16(Alo, Bh0, acc0, 0, 0, 0);
        acc0 = __builtin_amdgcn_mfma_f32_16x16x16f16(Ahi, Bl0, acc0, 0, 0, 0);
        acc0 = __builtin_amdgcn_mfma_f32_16x16x16f16(Ahi, Bh0, acc0, 0, 0, 0);
        acc1 = __builtin_amdgcn_mfma_f32_16x16x16f16(Alo, Bh1, acc1, 0, 0, 0);
        acc1 = __builtin_amdgcn_mfma_f32_16x16x16f16(Ahi, Bl1, acc1, 0, 0, 0);
        acc1 = __builtin_amdgcn_mfma_f32_16x16x16f16(Ahi, Bh1, acc1, 0, 0, 0);
    }

#pragma unroll
    for (int i = 0; i < 4; i++) {
        const int t = t0 + tt * 16 + 4 * q + i;
        if (t < Tn) {
            float* rowp = out + ((size_t)b * Tn + t) * Rn + rcol;
            rowp[0]  = acc0[i];
            rowp[16] = acc1[i];
        }
    }
}

// ---------------- C3: wave-per-t finish: up = raw + agg@lin_e + b -> LN ----------------
__global__ __launch_bounds__(256) void ln_kernel(
    const float* __restrict__ agg_ws, const int* __restrict__ len_ws,
    const float* __restrict__ lin_e_w, const float* __restrict__ lin_e_b,
    const float* __restrict__ ln_o_g, const float* __restrict__ ln_o_b,
    float* __restrict__ out)
{
    const int b = blockIdx.y, tid = threadIdx.x;
    const int sub = tid >> 6, lane = tid & 63;
    const int t = blockIdx.x * 4 + sub;
    const int r0 = lane * 4;
    float* __restrict__ row = out + ((size_t)b * Tn + t) * Rn;
    const int len = len_ws[b];
    if (t >= len) {
        *(float4*)(row + r0) = make_float4(0.f, 0.f, 0.f, 0.f);
        return;
    }

    float4 acc = *(const float4*)(row + r0);
    {
        const float4 be = *(const float4*)(lin_e_b + r0);
        acc.x += be.x; acc.y += be.y; acc.z += be.z; acc.w += be.w;
    }
    const float* aggp = agg_ws + ((size_t)b * Tn + t) * 16;
#pragma unroll
    for (int p = 0; p < 16; p++) {
        const float a = aggp[p];
        const float4 l = *(const float4*)(lin_e_w + p * Rn + r0);
        acc.x = fmaf(a, l.x, acc.x); acc.y = fmaf(a, l.y, acc.y);
        acc.z = fmaf(a, l.z, acc.z); acc.w = fmaf(a, l.w, acc.w);
    }

    float s = (acc.x + acc.y) + (acc.z + acc.w);
#pragma unroll
    for (int off = 1; off <= 32; off <<= 1) s += __shfl_xor(s, off, 64);
    const float mu = s * (1.f / Rn);
    const float d0 = acc.x - mu, d1 = acc.y - mu, d2 = acc.z - mu, d3 = acc.w - mu;
    float vr = d0 * d0 + d1 * d1 + d2 * d2 + d3 * d3;
#pragma unroll
    for (int off = 1; off <= 32; off <<= 1) vr += __shfl_xor(vr, off, 64);
    const float rs = rsqrtf(vr * (1.f / Rn) + 1e-5f);

    const float4 g = *(const float4*)(ln_o_g + r0);
    const float4 bb = *(const float4*)(ln_o_b + r0);
    float4 res;
    res.x = d0 * rs * g.x + bb.x;
    res.y = d1 * rs * g.y + bb.y;
    res.z = d2 * rs * g.z + bb.z;
    res.w = d3 * rs * g.w + bb.w;
    *(float4*)(row + r0) = res;
}

// ---------------- launch ----------------
extern "C" void kernel_launch(void* const* d_in, const int* in_sizes, int n_in,
                              void* d_out, int out_size, void* d_ws, size_t ws_size,
                              hipStream_t stream)
{
    const float* dur       = (const float*)d_in[0];
    const float* V         = (const float*)d_in[1];
    const unsigned char* text_mask = (const unsigned char*)d_in[3];
    const float* conv_c_w  = (const float*)d_in[4];
    const float* conv_c_b  = (const float*)d_in[5];
    const float* bn_c_g    = (const float*)d_in[6];
    const float* bn_c_b    = (const float*)d_in[7];
    const float* ln_c_g    = (const float*)d_in[8];
    const float* ln_c_b    = (const float*)d_in[9];
    const float* conv_w_w  = (const float*)d_in[10];
    const float* conv_w_b  = (const float*)d_in[11];
    const float* bn_w_g    = (const float*)d_in[12];
    const float* bn_w_b    = (const float*)d_in[13];
    const float* ln_w_g    = (const float*)d_in[14];
    const float* ln_w_b    = (const float*)d_in[15];
    const float* swc_w1    = (const float*)d_in[16];
    const float* swc_b1    = (const float*)d_in[17];
    const float* swc_w2    = (const float*)d_in[18];
    const float* swc_b2    = (const float*)d_in[19];
    const float* sww_w1    = (const float*)d_in[20];
    const float* sww_b1    = (const float*)d_in[21];
    const float* sww_w2    = (const float*)d_in[22];
    const float* sww_b2    = (const float*)d_in[23];
    const float* proj_w_w  = (const float*)d_in[24];
    const float* proj_w_b  = (const float*)d_in[25];
    const float* lin_e_w   = (const float*)d_in[26];
    const float* lin_e_b   = (const float*)d_in[27];
    const float* ln_o_g    = (const float*)d_in[28];
    const float* ln_o_b    = (const float*)d_in[29];

    float* out = (float*)d_out;
    float* wsf = (float*)d_ws;
    int*   len_ws   = (int*)wsf;                // 16 (pad 64)
    float* alpha_ws = wsf + 64;                 // 32 (pad 64)
    float* ab_ws    = wsf + 128;                // 16*8192 = 131072 (transposed [b][c][k])
    float* scratch  = ab_ws + 131072;           // part 524288, then aliased agg 256000
    float* part     = scratch;
    float* agg_ws   = scratch;

    conv_partial_kernel<<<dim3(8, Bn), dim3(256), 0, stream>>>(V, conv_w_w, conv_c_w, part);
    conv_scan_finish_kernel<<<dim3(Bn), dim3(256), 0, stream>>>(
        dur, part, text_mask,
        conv_w_b, bn_w_g, bn_w_b, ln_w_g, ln_w_b,
        conv_c_b, bn_c_g, bn_c_b, ln_c_g, ln_c_b,
        sww_w1, sww_b1, swc_w1, swc_b1,
        alpha_ws, ab_ws, len_ws, out);
    logits_kernel<<<dim3((Tn + 15) / 16, Bn), dim3(256), 0, stream>>>(
        text_mask, len_ws, alpha_ws, ab_ws,
        sww_w2, sww_b2, proj_w_w, proj_w_b,
        swc_w2, swc_b2,
        agg_ws, out);
    matvec_mfma_kernel<<<dim3((Tn + 31) / 32, 4, Bn), dim3(256), 0, stream>>>(
        out + W_OFF, V, out);
    ln_kernel<<<dim3(Tn / 4, Bn), dim3(256), 0, stream>>>(
        agg_ws, len_ws, lin_e_w, lin_e_b, ln_o_g, ln_o_b, out);
}

// Round 11
// 160.336 us; speedup vs baseline: 2.2262x; 2.2262x over previous
//
#include <hip/hip_runtime.h>
#include <cstddef>

constexpr int Bn = 16, Kn = 256, Rn = 256, Tn = 1000, C8 = 8, SW = 16;
constexpr size_t UP_SZ    = (size_t)Bn * Tn * Rn;          // 4,096,000
constexpr size_t MASK_OFF = UP_SZ;                          // + 16,000
constexpr size_t LEN_OFF  = MASK_OFF + (size_t)Bn * Tn;     // + 16
constexpr size_t W_OFF    = LEN_OFF + Bn;                    // + 4,096,000

using half4_t = __attribute__((ext_vector_type(4))) _Float16;
using f32x4_t = __attribute__((ext_vector_type(4))) float;
using uint2_t = __attribute__((ext_vector_type(2))) unsigned int;

__device__ __forceinline__ float fast_rcp(float x) { return __builtin_amdgcn_rcpf(x); }
__device__ __forceinline__ float fast_exp2(float x) { return __builtin_amdgcn_exp2f(x); }
constexpr float LOG2E = 1.44269504088896340736f;
__device__ __forceinline__ float silu_f(float x) {
    return x * fast_rcp(1.f + fast_exp2(-LOG2E * x));
}

// pack 4 floats -> fp16 hi + lo halves
__device__ __forceinline__ void split4(const float x0, const float x1,
                                       const float x2, const float x3,
                                       half4_t& hi, half4_t& lo)
{
    const auto h01 = __builtin_amdgcn_cvt_pkrtz(x0, x1);
    const auto h23 = __builtin_amdgcn_cvt_pkrtz(x2, x3);
    uint2_t uh; uh.x = __builtin_bit_cast(unsigned int, h01);
    uh.y = __builtin_bit_cast(unsigned int, h23);
    hi = __builtin_bit_cast(half4_t, uh);
    const auto l01 = __builtin_amdgcn_cvt_pkrtz(x0 - (float)h01.x, x1 - (float)h01.y);
    const auto l23 = __builtin_amdgcn_cvt_pkrtz(x2 - (float)h23.x, x3 - (float)h23.y);
    uint2_t ul; ul.x = __builtin_bit_cast(unsigned int, l01);
    ul.y = __builtin_bit_cast(unsigned int, l23);
    lo = __builtin_bit_cast(half4_t, ul);
}

// ---------------- conv phase A: partial sums over r-chunks ----------------
__global__ __launch_bounds__(256) void conv_partial_kernel(
    const float* __restrict__ V,
    const float* __restrict__ wW, const float* __restrict__ wC,
    float* __restrict__ part)
{
    const int rc = blockIdx.x, b = blockIdx.y, k = threadIdx.x;
    constexpr int RPAD = 33;
    __shared__ float vt[258 * RPAD];
    if (k < 16) {
        const int row = (k < 8) ? 0 : 257;
        const int j = (k & 7) * 4;
        vt[row * RPAD + j] = 0.f; vt[row * RPAD + j + 1] = 0.f;
        vt[row * RPAD + j + 2] = 0.f; vt[row * RPAD + j + 3] = 0.f;
    }
    const float* vsrc = V + ((size_t)(b * Kn + k)) * Rn + rc * 32;
#pragma unroll
    for (int j = 0; j < 8; j++) {
        const float4 qv = *(const float4*)(vsrc + j * 4);
        float* dst = &vt[(k + 1) * RPAD + j * 4];
        dst[0] = qv.x; dst[1] = qv.y; dst[2] = qv.z; dst[3] = qv.w;
    }
    __syncthreads();

    float aw[C8], ac[C8];
#pragma unroll
    for (int c = 0; c < C8; c++) { aw[c] = 0.f; ac[c] = 0.f; }
    for (int dk = 0; dk < 3; dk++) {
        const float* wp = wW + (size_t)(dk * Rn + rc * 32) * C8;
        const float* cp = wC + (size_t)(dk * Rn + rc * 32) * C8;
        const float* vrow = &vt[(k + dk) * RPAD];
#pragma unroll 4
        for (int r = 0; r < 32; r++) {
            const float v = vrow[r];
#pragma unroll
            for (int c = 0; c < C8; c++) {
                aw[c] = fmaf(v, wp[r * C8 + c], aw[c]);
                ac[c] = fmaf(v, cp[r * C8 + c], ac[c]);
            }
        }
    }
    float* dst = part + ((size_t)(b * 8 + rc) * Kn + k) * 16;
    *(float4*)(dst + 0)  = make_float4(aw[0], aw[1], aw[2], aw[3]);
    *(float4*)(dst + 4)  = make_float4(aw[4], aw[5], aw[6], aw[7]);
    *(float4*)(dst + 8)  = make_float4(ac[0], ac[1], ac[2], ac[3]);
    *(float4*)(dst + 12) = make_float4(ac[4], ac[5], ac[6], ac[7]);
}

// ---------------- conv phase B (fused with scan): reduce + post + beta/alpha ----------------
__device__ __forceinline__ void conv_post(
    const float* acc, const float* cb, const float* bng, const float* bnb,
    const float* lng, const float* lnb, const float* w1, const float* b1,
    float* __restrict__ dst)
{
    const float bnscale = rsqrtf(1.f + 1e-5f);
    float x[C8];
    float mu = 0.f;
#pragma unroll
    for (int c = 0; c < C8; c++) {
        float v = (acc[c] + cb[c]) * (bng[c] * bnscale) + bnb[c];
        v = silu_f(v);
        x[c] = v; mu += v;
    }
    mu *= (1.f / C8);
    float var = 0.f;
#pragma unroll
    for (int c = 0; c < C8; c++) { float dd = x[c] - mu; var += dd * dd; }
    var *= (1.f / C8);
    const float rs = rsqrtf(var + 1e-5f);
    float y[C8];
#pragma unroll
    for (int c = 0; c < C8; c++) y[c] = (x[c] - mu) * rs * lng[c] + lnb[c];
#pragma unroll
    for (int c2 = 0; c2 < SW; c2++) {
        float a = b1[c2];
#pragma unroll
        for (int p = 0; p < C8; p++) a = fmaf(y[p], w1[(2 + p) * SW + c2], a);
        dst[c2] = a;
    }
}

__global__ __launch_bounds__(256) void conv_scan_finish_kernel(
    const float* __restrict__ dur,
    const float* __restrict__ part,
    const unsigned char* __restrict__ tmask_g,
    const float* __restrict__ bW, const float* __restrict__ bngW, const float* __restrict__ bnbW,
    const float* __restrict__ lngW, const float* __restrict__ lnbW,
    const float* __restrict__ bC, const float* __restrict__ bngC, const float* __restrict__ bnbC,
    const float* __restrict__ lngC, const float* __restrict__ lnbC,
    const float* __restrict__ sww_w1, const float* __restrict__ sww_b1,
    const float* __restrict__ swc_w1, const float* __restrict__ swc_b1,
    float* __restrict__ alpha_ws, float* __restrict__ ab_ws,
    int* __restrict__ len_ws, float* __restrict__ out)
{
    const int b = blockIdx.x, k = threadIdx.x;
    __shared__ float sc[Kn];
    const float d = dur[b * Kn + k];
    sc[k] = d;
    __syncthreads();
    for (int off = 1; off < Kn; off <<= 1) {
        float v = (k >= off) ? sc[k - off] : 0.f;
        __syncthreads();
        sc[k] += v;
        __syncthreads();
    }
    const float ek = sc[k];
    const float sk = ek - d;
    const float total = sc[Kn - 1];
    int len = (int)rintf(total);
    if (len > Tn) len = Tn;
    if (k == 0) { len_ws[b] = len; out[LEN_OFF + b] = (float)len; }
    for (int t = k; t < Tn; t += 256)
        out[MASK_OFF + (size_t)b * Tn + t] = (t >= len) ? 1.f : 0.f;
    if (b == 0 && k < 16) {
        alpha_ws[k]      = sww_w1[k] - sww_w1[SW + k];
        alpha_ws[16 + k] = swc_w1[k] - swc_w1[SW + k];
    }

    float aw[C8], ac[C8];
#pragma unroll
    for (int c = 0; c < C8; c++) { aw[c] = 0.f; ac[c] = 0.f; }
#pragma unroll 2
    for (int rc = 0; rc < 8; rc++) {
        const float4* p = (const float4*)(part + ((size_t)(b * 8 + rc) * Kn + k) * 16);
        const float4 q0 = p[0], q1 = p[1], q2 = p[2], q3 = p[3];
        aw[0] += q0.x; aw[1] += q0.y; aw[2] += q0.z; aw[3] += q0.w;
        aw[4] += q1.x; aw[5] += q1.y; aw[6] += q1.z; aw[7] += q1.w;
        ac[0] += q2.x; ac[1] += q2.y; ac[2] += q2.z; ac[3] += q2.w;
        ac[4] += q3.x; ac[5] += q3.y; ac[6] += q3.z; ac[7] += q3.w;
    }
    float basew[SW], basec[SW];
    conv_post(aw, bW, bngW, bnbW, lngW, lnbW, sww_w1, sww_b1, basew);
    conv_post(ac, bC, bngC, bnbC, lngC, lnbC, swc_w1, swc_b1, basec);

    const bool msk = tmask_g[b * Kn + k] != 0;
    float* dst = ab_ws + ((size_t)(b * Kn) + k) * 32;
#pragma unroll
    for (int c = 0; c < SW; c++) {
        const float w0w = sww_w1[c], w1w_ = sww_w1[SW + c];
        const float w0c = swc_w1[c], w1c_ = swc_w1[SW + c];
        dst[c]      = msk ? basew[c] : fmaf(ek, w1w_, fmaf(-sk, w0w, basew[c]));
        dst[16 + c] = msk ? basec[c] : fmaf(ek, w1c_, fmaf(-sk, w0c, basec[c]));
    }
}

// ---------------- C1: swish blocks via MFMA + softmax + W + agg (8 t/block) ----------------
__global__ __launch_bounds__(256) void logits_kernel(
    const unsigned char* __restrict__ tm, const int* __restrict__ len_ws,
    const float* __restrict__ alpha_ws, const float* __restrict__ ab_ws,
    const float* __restrict__ sww_w2, const float* __restrict__ sww_b2,
    const float* __restrict__ proj_w, const float* __restrict__ proj_b,
    const float* __restrict__ swc_w2, const float* __restrict__ swc_b2,
    float* __restrict__ agg_ws, float* __restrict__ out)
{
    const int t0 = blockIdx.x * 8, b = blockIdx.y, tid = threadIdx.x;
    const int lane = tid & 63, w = tid >> 6, q = lane >> 4, m = lane & 15;
    const int len = len_ws[b];

    __shared__ __align__(16) unsigned int hA[256 * 10];  // h_w hi
    __shared__ __align__(16) unsigned int hB[256 * 10];  // h_w lo
    __shared__ __align__(16) unsigned int hC[256 * 10];  // h_c
    __shared__ float red[8];
    __shared__ __align__(16) float aggw[2][4][16];

    // per-thread beta vectors (alpha is uniform -> SGPRs via alpha_ws[const])
    float bw[16], bc[16];
    {
        const float4* bp = (const float4*)(ab_ws + (((size_t)b * Kn) + tid) * 32);
#pragma unroll
        for (int i = 0; i < 4; i++) {
            const float4 v = bp[i];
            bw[4*i] = v.x; bw[4*i+1] = v.y; bw[4*i+2] = v.z; bw[4*i+3] = v.w;
        }
#pragma unroll
        for (int i = 0; i < 4; i++) {
            const float4 v = bp[4 + i];
            bc[4*i] = v.x; bc[4*i+1] = v.y; bc[4*i+2] = v.z; bc[4*i+3] = v.w;
        }
    }
    const float mk = (tm[b * Kn + tid] != 0) ? 0.f : 1.f;

    // A-fragments (identical pattern to verified r5 kernel)
    half4_t AWhi, AWlo, ACf;
    float pj[4], b2wv[4], b2cv[4], mb[4];
#pragma unroll
    for (int i = 0; i < 4; i++) {
        const int c = 4 * q + i;
        const float vw = sww_w2[c * SW + m];
        const _Float16 hi = (_Float16)vw;
        AWhi[i] = hi;
        AWlo[i] = (_Float16)(vw - (float)hi);
        ACf[i]  = (_Float16)(swc_w2[c * SW + m]);
        pj[i]   = proj_w[c];
        b2wv[i] = sww_b2[c];
        b2cv[i] = swc_b2[c];
        mb[i]   = (tm[b * Kn + 64 * w + 16 * i + m] != 0) ? -INFINITY : 0.f;
    }
    const float pb = proj_b[0];

    int pend = -1, pendpar = 0;

    for (int ti = 0; ti < 8; ti++) {
        const int t = t0 + ti;
        float* __restrict__ W_out = out + W_OFF + ((size_t)b * Tn + t) * Kn;
        if (t >= len) { W_out[tid] = 0.f; continue; }   // uniform over block
        const float u = (float)(t + 1);
        const float umk = u * mk;

        // ---- layer-1: arg = umk*alpha[c] + beta[k][c]; silu; fp16 pack ----
#pragma unroll
        for (int p = 0; p < 8; p++) {
            const float x0 = fmaf(umk, alpha_ws[2*p],   bw[2*p]);
            const float x1 = fmaf(umk, alpha_ws[2*p+1], bw[2*p+1]);
            const float h0 = silu_f(x0), h1 = silu_f(x1);
            const auto hp = __builtin_amdgcn_cvt_pkrtz(h0, h1);
            hA[tid * 10 + p] = __builtin_bit_cast(unsigned int, hp);
            const float l0 = h0 - (float)hp.x, l1 = h1 - (float)hp.y;
            hB[tid * 10 + p] = __builtin_bit_cast(unsigned int,
                                __builtin_amdgcn_cvt_pkrtz(l0, l1));
            const float y0 = fmaf(umk, alpha_ws[16 + 2*p],   bc[2*p]);
            const float y1 = fmaf(umk, alpha_ws[16 + 2*p+1], bc[2*p+1]);
            hC[tid * 10 + p] = __builtin_bit_cast(unsigned int,
                                __builtin_amdgcn_cvt_pkrtz(silu_f(y0), silu_f(y1)));
        }
        // wave-local rows: in-wave DS ordering suffices (no barrier needed)

        // ---- MFMA W-path: split-fp16, 3 mfma per 16x16 tile ----
        f32x4_t o[4];
#pragma unroll
        for (int j = 0; j < 4; j++) {
            const int row = 64 * w + 16 * j + m;
            const uint2_t rh = *(const uint2_t*)&hA[row * 10 + 2 * q];
            const uint2_t rl = *(const uint2_t*)&hB[row * 10 + 2 * q];
            const half4_t bh = __builtin_bit_cast(half4_t, rh);
            const half4_t bl = __builtin_bit_cast(half4_t, rl);
            f32x4_t acc = {0.f, 0.f, 0.f, 0.f};
            acc = __builtin_amdgcn_mfma_f32_16x16x16f16(AWlo, bh, acc, 0, 0, 0);
            acc = __builtin_amdgcn_mfma_f32_16x16x16f16(AWhi, bl, acc, 0, 0, 0);
            acc = __builtin_amdgcn_mfma_f32_16x16x16f16(AWhi, bh, acc, 0, 0, 0);
            o[j] = acc;
        }

        // ---- logit: silu(o + b2) . proj, reduce over c2 ----
        float lg[4];
#pragma unroll
        for (int j = 0; j < 4; j++) {
            float s = silu_f(o[j][0] + b2wv[0]) * pj[0];
            s = fmaf(silu_f(o[j][1] + b2wv[1]), pj[1], s);
            s = fmaf(silu_f(o[j][2] + b2wv[2]), pj[2], s);
            s = fmaf(silu_f(o[j][3] + b2wv[3]), pj[3], s);
            s += __shfl_xor(s, 16, 64);
            s += __shfl_xor(s, 32, 64);
            lg[j] = s + pb + mb[j];
        }

        // ---- softmax over 256 rows ----
        float mx = fmaxf(fmaxf(lg[0], lg[1]), fmaxf(lg[2], lg[3]));
#pragma unroll
        for (int off = 1; off <= 8; off <<= 1) mx = fmaxf(mx, __shfl_xor(mx, off, 64));
        if (lane == 0) red[w] = mx;
        __syncthreads();                        // S2: publish wave maxima
        if (pend >= 0) {                        // deferred agg finalize for t-1
            if (tid < 16)
                agg_ws[((size_t)b * Tn + pend) * 16 + tid] =
                    aggw[pendpar][0][tid] + aggw[pendpar][1][tid] +
                    aggw[pendpar][2][tid] + aggw[pendpar][3][tid];
            pend = -1;
        }
        const float M = fmaxf(fmaxf(red[0], red[1]), fmaxf(red[2], red[3]));
        float pex[4];
#pragma unroll
        for (int j = 0; j < 4; j++) pex[j] = fast_exp2(LOG2E * (lg[j] - M));
        float ssum = (pex[0] + pex[1]) + (pex[2] + pex[3]);
#pragma unroll
        for (int off = 1; off <= 8; off <<= 1) ssum += __shfl_xor(ssum, off, 64);
        if (lane == 0) red[4 + w] = ssum;
        __syncthreads();                        // S3: publish wave sums
        const float inv = fast_rcp(red[4] + red[5] + red[6] + red[7]);
        float wgt[4];
#pragma unroll
        for (int j = 0; j < 4; j++) wgt[j] = pex[j] * inv;
        if (q == 0) {
#pragma unroll
            for (int j = 0; j < 4; j++) W_out[64 * w + 16 * j + m] = wgt[j];
        }

        // ---- MFMA C-path (single fp16 from hC) + weighted agg ----
        f32x4_t ap = {0.f, 0.f, 0.f, 0.f};
#pragma unroll
        for (int j = 0; j < 4; j++) {
            const int row = 64 * w + 16 * j + m;
            const uint2_t rc2 = *(const uint2_t*)&hC[row * 10 + 2 * q];
            f32x4_t zz = {0.f, 0.f, 0.f, 0.f};
            const f32x4_t oc = __builtin_amdgcn_mfma_f32_16x16x16f16(
                ACf, __builtin_bit_cast(half4_t, rc2), zz, 0, 0, 0);
#pragma unroll
            for (int i = 0; i < 4; i++)
                ap[i] = fmaf(silu_f(oc[i] + b2cv[i]), wgt[j], ap[i]);
        }
#pragma unroll
        for (int off = 1; off <= 8; off <<= 1) {
            ap[0] += __shfl_xor(ap[0], off, 64);
            ap[1] += __shfl_xor(ap[1], off, 64);
            ap[2] += __shfl_xor(ap[2], off, 64);
            ap[3] += __shfl_xor(ap[3], off, 64);
        }
        if (m == 0)
            *(float4*)&aggw[ti & 1][w][4 * q] = make_float4(ap[0], ap[1], ap[2], ap[3]);
        pend = t; pendpar = ti & 1;
    }
    if (pend >= 0) {
        __syncthreads();
        if (tid < 16)
            agg_ws[((size_t)b * Tn + pend) * 16 + tid] =
                aggw[pendpar][0][tid] + aggw[pendpar][1][tid] +
                aggw[pendpar][2][tid] + aggw[pendpar][3][tid];
    }
}

// ---------- C2: merged matvec (MFMA, 16t x 256r) + LN finish, raw stays in LDS ----------
__global__ __launch_bounds__(256) void matvec_ln_kernel(
    const float* __restrict__ Wg, const float* __restrict__ V,
    const float* __restrict__ agg_ws, const int* __restrict__ len_ws,
    const float* __restrict__ lin_e_w, const float* __restrict__ lin_e_b,
    const float* __restrict__ ln_o_g, const float* __restrict__ ln_o_b,
    float* __restrict__ out)
{
    const int t0 = blockIdx.x * 16, b = blockIdx.y, tid = threadIdx.x;
    const int lane = tid & 63, w = tid >> 6, q = lane >> 4, m = lane & 15;
    const int len = len_ws[b];

    __shared__ __align__(16) float Wl[16 * 256];   // 16 KiB, XOR-swizzled float4 slots
    __shared__ __align__(16) float raw[16 * 260];  // 16.25 KiB

    // stage W tile: row = t-local, swizzle float4-slot ^= (row&7)
    const float4* Wg4 = (const float4*)Wg;
#pragma unroll
    for (int ch = 0; ch < 4; ch++) {
        const int idx = ch * 256 + tid;
        const int row = idx >> 6, sl = idx & 63;
        const int t = t0 + row;
        const float4 v = (t < Tn) ? Wg4[((size_t)b * Tn + t) * 64 + sl]
                                  : make_float4(0.f, 0.f, 0.f, 0.f);
        *(float4*)&Wl[row * 256 + ((sl ^ (row & 7)) << 2)] = v;
    }
    __syncthreads();

    // matvec: verified r9 phase (A row = m (t-local), B from V coalesced)
    f32x4_t acc[4];
#pragma unroll
    for (int i = 0; i < 4; i++) acc[i] = f32x4_t{0.f, 0.f, 0.f, 0.f};
    const float* Vb = V + (size_t)b * Kn * Rn;

#pragma unroll
    for (int ks = 0; ks < 16; ks++) {
        const float4 wv = *(const float4*)&Wl[m * 256 + (((4 * ks + q) ^ (m & 7)) << 2)];
        half4_t Ahi, Alo;
        split4(wv.x, wv.y, wv.z, wv.w, Ahi, Alo);
        const float* vp = Vb + (size_t)(ks * 16 + 4 * q) * Rn;
#pragma unroll
        for (int rt = 0; rt < 4; rt++) {
            const int rcol = w * 64 + rt * 16 + m;
            const float b0 = vp[rcol],          b1 = vp[Rn + rcol];
            const float b2 = vp[2 * Rn + rcol], b3 = vp[3 * Rn + rcol];
            half4_t Bh, Bl;
            split4(b0, b1, b2, b3, Bh, Bl);
            acc[rt] = __builtin_amdgcn_mfma_f32_16x16x16f16(Alo, Bh, acc[rt], 0, 0, 0);
            acc[rt] = __builtin_amdgcn_mfma_f32_16x16x16f16(Ahi, Bl, acc[rt], 0, 0, 0);
            acc[rt] = __builtin_amdgcn_mfma_f32_16x16x16f16(Ahi, Bh, acc[rt], 0, 0, 0);
        }
    }
#pragma unroll
    for (int rt = 0; rt < 4; rt++) {
#pragma unroll
        for (int i = 0; i < 4; i++)
            raw[(4 * q + i) * 260 + w * 64 + rt * 16 + m] = acc[rt][i];
    }
    __syncthreads();

    // LN phase: wave w handles t_local 4w..4w+3
#pragma unroll
    for (int j = 0; j < 4; j++) {
        const int tl = 4 * w + j;
        const int t = t0 + tl;
        if (t >= Tn) continue;
        float* __restrict__ row = out + ((size_t)b * Tn + t) * Rn;
        const int r0 = lane * 4;
        if (t >= len) {
            *(float4*)(row + r0) = make_float4(0.f, 0.f, 0.f, 0.f);
            continue;
        }
        float4 a4 = *(const float4*)&raw[tl * 260 + r0];
        {
            const float4 be = *(const float4*)(lin_e_b + r0);
            a4.x += be.x; a4.y += be.y; a4.z += be.z; a4.w += be.w;
        }
        const float* aggp = agg_ws + ((size_t)b * Tn + t) * 16;
#pragma unroll
        for (int p = 0; p < 16; p++) {
            const float a = aggp[p];
            const float4 l = *(const float4*)(lin_e_w + p * Rn + r0);
            a4.x = fmaf(a, l.x, a4.x); a4.y = fmaf(a, l.y, a4.y);
            a4.z = fmaf(a, l.z, a4.z); a4.w = fmaf(a, l.w, a4.w);
        }
        float s = (a4.x + a4.y) + (a4.z + a4.w);
#pragma unroll
        for (int off = 1; off <= 32; off <<= 1) s += __shfl_xor(s, off, 64);
        const float mu = s * (1.f / Rn);
        const float d0 = a4.x - mu, d1 = a4.y - mu, d2 = a4.z - mu, d3 = a4.w - mu;
        float vr = d0 * d0 + d1 * d1 + d2 * d2 + d3 * d3;
#pragma unroll
        for (int off = 1; off <= 32; off <<= 1) vr += __shfl_xor(vr, off, 64);
        const float rs = rsqrtf(vr * (1.f / Rn) + 1e-5f);
        const float4 g = *(const float4*)(ln_o_g + r0);
        const float4 bb = *(const float4*)(ln_o_b + r0);
        float4 res;
        res.x = d0 * rs * g.x + bb.x;
        res.y = d1 * rs * g.y + bb.y;
        res.z = d2 * rs * g.z + bb.z;
        res.w = d3 * rs * g.w + bb.w;
        *(float4*)(row + r0) = res;
    }
}

// ---------------- launch ----------------
extern "C" void kernel_launch(void* const* d_in, const int* in_sizes, int n_in,
                              void* d_out, int out_size, void* d_ws, size_t ws_size,
                              hipStream_t stream)
{
    const float* dur       = (const float*)d_in[0];
    const float* V         = (const float*)d_in[1];
    const unsigned char* text_mask = (const unsigned char*)d_in[3];
    const float* conv_c_w  = (const float*)d_in[4];
    const float* conv_c_b  = (const float*)d_in[5];
    const float* bn_c_g    = (const float*)d_in[6];
    const float* bn_c_b    = (const float*)d_in[7];
    const float* ln_c_g    = (const float*)d_in[8];
    const float* ln_c_b    = (const float*)d_in[9];
    const float* conv_w_w  = (const float*)d_in[10];
    const float* conv_w_b  = (const float*)d_in[11];
    const float* bn_w_g    = (const float*)d_in[12];
    const float* bn_w_b    = (const float*)d_in[13];
    const float* ln_w_g    = (const float*)d_in[14];
    const float* ln_w_b    = (const float*)d_in[15];
    const float* swc_w1    = (const float*)d_in[16];
    const float* swc_b1    = (const float*)d_in[17];
    const float* swc_w2    = (const float*)d_in[18];
    const float* swc_b2    = (const float*)d_in[19];
    const float* sww_w1    = (const float*)d_in[20];
    const float* sww_b1    = (const float*)d_in[21];
    const float* sww_w2    = (const float*)d_in[22];
    const float* sww_b2    = (const float*)d_in[23];
    const float* proj_w_w  = (const float*)d_in[24];
    const float* proj_w_b  = (const float*)d_in[25];
    const float* lin_e_w   = (const float*)d_in[26];
    const float* lin_e_b   = (const float*)d_in[27];
    const float* ln_o_g    = (const float*)d_in[28];
    const float* ln_o_b    = (const float*)d_in[29];

    float* out = (float*)d_out;
    float* wsf = (float*)d_ws;
    int*   len_ws   = (int*)wsf;                // 16 (pad 64)
    float* alpha_ws = wsf + 64;                 // 32 (pad 64)
    float* ab_ws    = wsf + 128;                // 16*256*32 = 131072
    float* scratch  = ab_ws + 131072;           // part 524288, then aliased agg 256000
    float* part     = scratch;
    float* agg_ws   = scratch;

    conv_partial_kernel<<<dim3(8, Bn), dim3(256), 0, stream>>>(V, conv_w_w, conv_c_w, part);
    conv_scan_finish_kernel<<<dim3(Bn), dim3(256), 0, stream>>>(
        dur, part, text_mask,
        conv_w_b, bn_w_g, bn_w_b, ln_w_g, ln_w_b,
        conv_c_b, bn_c_g, bn_c_b, ln_c_g, ln_c_b,
        sww_w1, sww_b1, swc_w1, swc_b1,
        alpha_ws, ab_ws, len_ws, out);
    logits_kernel<<<dim3(Tn / 8, Bn), dim3(256), 0, stream>>>(
        text_mask, len_ws, alpha_ws, ab_ws,
        sww_w2, sww_b2, proj_w_w, proj_w_b,
        swc_w2, swc_b2,
        agg_ws, out);
    matvec_ln_kernel<<<dim3((Tn + 15) / 16, Bn), dim3(256), 0, stream>>>(
        out + W_OFF, V, agg_ws, len_ws,
        lin_e_w, lin_e_b, ln_o_g, ln_o_b, out);
}

// Round 12
// 159.978 us; speedup vs baseline: 2.2312x; 1.0022x over previous
//
#include <hip/hip_runtime.h>
#include <cstddef>

constexpr int Bn = 16, Kn = 256, Rn = 256, Tn = 1000, C8 = 8, SW = 16;
constexpr size_t UP_SZ    = (size_t)Bn * Tn * Rn;          // 4,096,000
constexpr size_t MASK_OFF = UP_SZ;                          // + 16,000
constexpr size_t LEN_OFF  = MASK_OFF + (size_t)Bn * Tn;     // + 16
constexpr size_t W_OFF    = LEN_OFF + Bn;                    // + 4,096,000

using half4_t = __attribute__((ext_vector_type(4))) _Float16;
using f32x4_t = __attribute__((ext_vector_type(4))) float;
using uint2_t = __attribute__((ext_vector_type(2))) unsigned int;

__device__ __forceinline__ float fast_rcp(float x) { return __builtin_amdgcn_rcpf(x); }
__device__ __forceinline__ float fast_exp2(float x) { return __builtin_amdgcn_exp2f(x); }
constexpr float LOG2E = 1.44269504088896340736f;
__device__ __forceinline__ float silu_f(float x) {
    return x * fast_rcp(1.f + fast_exp2(-LOG2E * x));
}

// pack 4 floats -> fp16 hi + lo halves
__device__ __forceinline__ void split4(const float x0, const float x1,
                                       const float x2, const float x3,
                                       half4_t& hi, half4_t& lo)
{
    const auto h01 = __builtin_amdgcn_cvt_pkrtz(x0, x1);
    const auto h23 = __builtin_amdgcn_cvt_pkrtz(x2, x3);
    uint2_t uh; uh.x = __builtin_bit_cast(unsigned int, h01);
    uh.y = __builtin_bit_cast(unsigned int, h23);
    hi = __builtin_bit_cast(half4_t, uh);
    const auto l01 = __builtin_amdgcn_cvt_pkrtz(x0 - (float)h01.x, x1 - (float)h01.y);
    const auto l23 = __builtin_amdgcn_cvt_pkrtz(x2 - (float)h23.x, x3 - (float)h23.y);
    uint2_t ul; ul.x = __builtin_bit_cast(unsigned int, l01);
    ul.y = __builtin_bit_cast(unsigned int, l23);
    lo = __builtin_bit_cast(half4_t, ul);
}

// ---------------- conv phase A: partial sums over r-chunks ----------------
__global__ __launch_bounds__(256) void conv_partial_kernel(
    const float* __restrict__ V,
    const float* __restrict__ wW, const float* __restrict__ wC,
    float* __restrict__ part)
{
    const int rc = blockIdx.x, b = blockIdx.y, k = threadIdx.x;
    constexpr int RPAD = 33;
    __shared__ float vt[258 * RPAD];
    if (k < 16) {
        const int row = (k < 8) ? 0 : 257;
        const int j = (k & 7) * 4;
        vt[row * RPAD + j] = 0.f; vt[row * RPAD + j + 1] = 0.f;
        vt[row * RPAD + j + 2] = 0.f; vt[row * RPAD + j + 3] = 0.f;
    }
    const float* vsrc = V + ((size_t)(b * Kn + k)) * Rn + rc * 32;
#pragma unroll
    for (int j = 0; j < 8; j++) {
        const float4 qv = *(const float4*)(vsrc + j * 4);
        float* dst = &vt[(k + 1) * RPAD + j * 4];
        dst[0] = qv.x; dst[1] = qv.y; dst[2] = qv.z; dst[3] = qv.w;
    }
    __syncthreads();

    float aw[C8], ac[C8];
#pragma unroll
    for (int c = 0; c < C8; c++) { aw[c] = 0.f; ac[c] = 0.f; }
    for (int dk = 0; dk < 3; dk++) {
        const float* wp = wW + (size_t)(dk * Rn + rc * 32) * C8;
        const float* cp = wC + (size_t)(dk * Rn + rc * 32) * C8;
        const float* vrow = &vt[(k + dk) * RPAD];
#pragma unroll 4
        for (int r = 0; r < 32; r++) {
            const float v = vrow[r];
#pragma unroll
            for (int c = 0; c < C8; c++) {
                aw[c] = fmaf(v, wp[r * C8 + c], aw[c]);
                ac[c] = fmaf(v, cp[r * C8 + c], ac[c]);
            }
        }
    }
    float* dst = part + ((size_t)(b * 8 + rc) * Kn + k) * 16;
    *(float4*)(dst + 0)  = make_float4(aw[0], aw[1], aw[2], aw[3]);
    *(float4*)(dst + 4)  = make_float4(aw[4], aw[5], aw[6], aw[7]);
    *(float4*)(dst + 8)  = make_float4(ac[0], ac[1], ac[2], ac[3]);
    *(float4*)(dst + 12) = make_float4(ac[4], ac[5], ac[6], ac[7]);
}

// ---------------- conv phase B (fused with scan): reduce + post + beta/alpha ----------------
__device__ __forceinline__ void conv_post(
    const float* acc, const float* cb, const float* bng, const float* bnb,
    const float* lng, const float* lnb, const float* w1, const float* b1,
    float* __restrict__ dst)
{
    const float bnscale = rsqrtf(1.f + 1e-5f);
    float x[C8];
    float mu = 0.f;
#pragma unroll
    for (int c = 0; c < C8; c++) {
        float v = (acc[c] + cb[c]) * (bng[c] * bnscale) + bnb[c];
        v = silu_f(v);
        x[c] = v; mu += v;
    }
    mu *= (1.f / C8);
    float var = 0.f;
#pragma unroll
    for (int c = 0; c < C8; c++) { float dd = x[c] - mu; var += dd * dd; }
    var *= (1.f / C8);
    const float rs = rsqrtf(var + 1e-5f);
    float y[C8];
#pragma unroll
    for (int c = 0; c < C8; c++) y[c] = (x[c] - mu) * rs * lng[c] + lnb[c];
#pragma unroll
    for (int c2 = 0; c2 < SW; c2++) {
        float a = b1[c2];
#pragma unroll
        for (int p = 0; p < C8; p++) a = fmaf(y[p], w1[(2 + p) * SW + c2], a);
        dst[c2] = a;
    }
}

__global__ __launch_bounds__(256) void conv_scan_finish_kernel(
    const float* __restrict__ dur,
    const float* __restrict__ part,
    const unsigned char* __restrict__ tmask_g,
    const float* __restrict__ bW, const float* __restrict__ bngW, const float* __restrict__ bnbW,
    const float* __restrict__ lngW, const float* __restrict__ lnbW,
    const float* __restrict__ bC, const float* __restrict__ bngC, const float* __restrict__ bnbC,
    const float* __restrict__ lngC, const float* __restrict__ lnbC,
    const float* __restrict__ sww_w1, const float* __restrict__ sww_b1,
    const float* __restrict__ swc_w1, const float* __restrict__ swc_b1,
    float* __restrict__ alpha_ws, float* __restrict__ ab_ws,
    int* __restrict__ len_ws, float* __restrict__ out)
{
    const int b = blockIdx.x, k = threadIdx.x;
    __shared__ float sc[Kn];
    const float d = dur[b * Kn + k];
    sc[k] = d;
    __syncthreads();
    for (int off = 1; off < Kn; off <<= 1) {
        float v = (k >= off) ? sc[k - off] : 0.f;
        __syncthreads();
        sc[k] += v;
        __syncthreads();
    }
    const float ek = sc[k];
    const float sk = ek - d;
    const float total = sc[Kn - 1];
    int len = (int)rintf(total);
    if (len > Tn) len = Tn;
    if (k == 0) { len_ws[b] = len; out[LEN_OFF + b] = (float)len; }
    for (int t = k; t < Tn; t += 256)
        out[MASK_OFF + (size_t)b * Tn + t] = (t >= len) ? 1.f : 0.f;
    if (b == 0 && k < 16) {
        alpha_ws[k]      = sww_w1[k] - sww_w1[SW + k];
        alpha_ws[16 + k] = swc_w1[k] - swc_w1[SW + k];
    }

    float aw[C8], ac[C8];
#pragma unroll
    for (int c = 0; c < C8; c++) { aw[c] = 0.f; ac[c] = 0.f; }
#pragma unroll 2
    for (int rc = 0; rc < 8; rc++) {
        const float4* p = (const float4*)(part + ((size_t)(b * 8 + rc) * Kn + k) * 16);
        const float4 q0 = p[0], q1 = p[1], q2 = p[2], q3 = p[3];
        aw[0] += q0.x; aw[1] += q0.y; aw[2] += q0.z; aw[3] += q0.w;
        aw[4] += q1.x; aw[5] += q1.y; aw[6] += q1.z; aw[7] += q1.w;
        ac[0] += q2.x; ac[1] += q2.y; ac[2] += q2.z; ac[3] += q2.w;
        ac[4] += q3.x; ac[5] += q3.y; ac[6] += q3.z; ac[7] += q3.w;
    }
    float basew[SW], basec[SW];
    conv_post(aw, bW, bngW, bnbW, lngW, lnbW, sww_w1, sww_b1, basew);
    conv_post(ac, bC, bngC, bnbC, lngC, lnbC, swc_w1, swc_b1, basec);

    const bool msk = tmask_g[b * Kn + k] != 0;
    float* dst = ab_ws + ((size_t)(b * Kn) + k) * 32;
#pragma unroll
    for (int c = 0; c < SW; c++) {
        const float w0w = sww_w1[c], w1w_ = sww_w1[SW + c];
        const float w0c = swc_w1[c], w1c_ = swc_w1[SW + c];
        dst[c]      = msk ? basew[c] : fmaf(ek, w1w_, fmaf(-sk, w0w, basew[c]));
        dst[16 + c] = msk ? basec[c] : fmaf(ek, w1c_, fmaf(-sk, w0c, basec[c]));
    }
}

// ---------------- C1: swish blocks via MFMA + softmax + W + agg (8 t/block) ----------------
// hC eliminated: C-path layer-1 runs AFTER the W-path MFMA reads and reuses hA
// (rows are wave-local: thread tid writes row tid; wave w's MFMAs read rows
// 64w..64w+63 only -> in-wave DS ordering suffices, no barrier).
__global__ __launch_bounds__(256) void logits_kernel(
    const unsigned char* __restrict__ tm, const int* __restrict__ len_ws,
    const float* __restrict__ alpha_ws, const float* __restrict__ ab_ws,
    const float* __restrict__ sww_w2, const float* __restrict__ sww_b2,
    const float* __restrict__ proj_w, const float* __restrict__ proj_b,
    const float* __restrict__ swc_w2, const float* __restrict__ swc_b2,
    float* __restrict__ agg_ws, float* __restrict__ out)
{
    const int t0 = blockIdx.x * 8, b = blockIdx.y, tid = threadIdx.x;
    const int lane = tid & 63, w = tid >> 6, q = lane >> 4, m = lane & 15;
    const int len = len_ws[b];

    __shared__ __align__(16) unsigned int hA[256 * 10];  // h_w hi, then reused for h_c
    __shared__ __align__(16) unsigned int hB[256 * 10];  // h_w lo
    __shared__ float red[8];
    __shared__ __align__(16) float aggw[2][4][16];

    // per-thread beta vectors (alpha is uniform -> SGPRs via alpha_ws[const])
    float bw[16], bc[16];
    {
        const float4* bp = (const float4*)(ab_ws + (((size_t)b * Kn) + tid) * 32);
#pragma unroll
        for (int i = 0; i < 4; i++) {
            const float4 v = bp[i];
            bw[4*i] = v.x; bw[4*i+1] = v.y; bw[4*i+2] = v.z; bw[4*i+3] = v.w;
        }
#pragma unroll
        for (int i = 0; i < 4; i++) {
            const float4 v = bp[4 + i];
            bc[4*i] = v.x; bc[4*i+1] = v.y; bc[4*i+2] = v.z; bc[4*i+3] = v.w;
        }
    }
    const float mk = (tm[b * Kn + tid] != 0) ? 0.f : 1.f;

    // A-fragments (identical pattern to verified r5 kernel)
    half4_t AWhi, AWlo, ACf;
    float pj[4], b2wv[4], b2cv[4], mb[4];
#pragma unroll
    for (int i = 0; i < 4; i++) {
        const int c = 4 * q + i;
        const float vw = sww_w2[c * SW + m];
        const _Float16 hi = (_Float16)vw;
        AWhi[i] = hi;
        AWlo[i] = (_Float16)(vw - (float)hi);
        ACf[i]  = (_Float16)(swc_w2[c * SW + m]);
        pj[i]   = proj_w[c];
        b2wv[i] = sww_b2[c];
        b2cv[i] = swc_b2[c];
        mb[i]   = (tm[b * Kn + 64 * w + 16 * i + m] != 0) ? -INFINITY : 0.f;
    }
    const float pb = proj_b[0];

    int pend = -1, pendpar = 0;

    for (int ti = 0; ti < 8; ti++) {
        const int t = t0 + ti;
        float* __restrict__ W_out = out + W_OFF + ((size_t)b * Tn + t) * Kn;
        if (t >= len) { W_out[tid] = 0.f; continue; }   // uniform over block
        const float u = (float)(t + 1);
        const float umk = u * mk;

        // ---- W-path layer-1: arg = umk*alpha[c] + beta[k][c]; silu; fp16 pack ----
#pragma unroll
        for (int p = 0; p < 8; p++) {
            const float x0 = fmaf(umk, alpha_ws[2*p],   bw[2*p]);
            const float x1 = fmaf(umk, alpha_ws[2*p+1], bw[2*p+1]);
            const float h0 = silu_f(x0), h1 = silu_f(x1);
            const auto hp = __builtin_amdgcn_cvt_pkrtz(h0, h1);
            hA[tid * 10 + p] = __builtin_bit_cast(unsigned int, hp);
            const float l0 = h0 - (float)hp.x, l1 = h1 - (float)hp.y;
            hB[tid * 10 + p] = __builtin_bit_cast(unsigned int,
                                __builtin_amdgcn_cvt_pkrtz(l0, l1));
        }
        // wave-local rows: in-wave DS ordering suffices (no barrier needed)

        // ---- MFMA W-path: split-fp16, 3 mfma per 16x16 tile ----
        f32x4_t o[4];
#pragma unroll
        for (int j = 0; j < 4; j++) {
            const int row = 64 * w + 16 * j + m;
            const uint2_t rh = *(const uint2_t*)&hA[row * 10 + 2 * q];
            const uint2_t rl = *(const uint2_t*)&hB[row * 10 + 2 * q];
            const half4_t bh = __builtin_bit_cast(half4_t, rh);
            const half4_t bl = __builtin_bit_cast(half4_t, rl);
            f32x4_t acc = {0.f, 0.f, 0.f, 0.f};
            acc = __builtin_amdgcn_mfma_f32_16x16x16f16(AWlo, bh, acc, 0, 0, 0);
            acc = __builtin_amdgcn_mfma_f32_16x16x16f16(AWhi, bl, acc, 0, 0, 0);
            acc = __builtin_amdgcn_mfma_f32_16x16x16f16(AWhi, bh, acc, 0, 0, 0);
            o[j] = acc;
        }

        // ---- C-path layer-1 (AFTER W reads): reuse hA, wave-local ----
#pragma unroll
        for (int p = 0; p < 8; p++) {
            const float y0 = fmaf(umk, alpha_ws[16 + 2*p],   bc[2*p]);
            const float y1 = fmaf(umk, alpha_ws[16 + 2*p+1], bc[2*p+1]);
            hA[tid * 10 + p] = __builtin_bit_cast(unsigned int,
                                __builtin_amdgcn_cvt_pkrtz(silu_f(y0), silu_f(y1)));
        }

        // ---- logit: silu(o + b2) . proj, reduce over c2 ----
        float lg[4];
#pragma unroll
        for (int j = 0; j < 4; j++) {
            float s = silu_f(o[j][0] + b2wv[0]) * pj[0];
            s = fmaf(silu_f(o[j][1] + b2wv[1]), pj[1], s);
            s = fmaf(silu_f(o[j][2] + b2wv[2]), pj[2], s);
            s = fmaf(silu_f(o[j][3] + b2wv[3]), pj[3], s);
            s += __shfl_xor(s, 16, 64);
            s += __shfl_xor(s, 32, 64);
            lg[j] = s + pb + mb[j];
        }

        // ---- softmax over 256 rows ----
        float mx = fmaxf(fmaxf(lg[0], lg[1]), fmaxf(lg[2], lg[3]));
#pragma unroll
        for (int off = 1; off <= 8; off <<= 1) mx = fmaxf(mx, __shfl_xor(mx, off, 64));
        if (lane == 0) red[w] = mx;
        __syncthreads();                        // S2: publish wave maxima
        if (pend >= 0) {                        // deferred agg finalize for t-1
            if (tid < 16)
                agg_ws[((size_t)b * Tn + pend) * 16 + tid] =
                    aggw[pendpar][0][tid] + aggw[pendpar][1][tid] +
                    aggw[pendpar][2][tid] + aggw[pendpar][3][tid];
            pend = -1;
        }
        const float M = fmaxf(fmaxf(red[0], red[1]), fmaxf(red[2], red[3]));
        float pex[4];
#pragma unroll
        for (int j = 0; j < 4; j++) pex[j] = fast_exp2(LOG2E * (lg[j] - M));
        float ssum = (pex[0] + pex[1]) + (pex[2] + pex[3]);
#pragma unroll
        for (int off = 1; off <= 8; off <<= 1) ssum += __shfl_xor(ssum, off, 64);
        if (lane == 0) red[4 + w] = ssum;
        __syncthreads();                        // S3: publish wave sums
        const float inv = fast_rcp(red[4] + red[5] + red[6] + red[7]);
        float wgt[4];
#pragma unroll
        for (int j = 0; j < 4; j++) wgt[j] = pex[j] * inv;
        if (q == 0) {
#pragma unroll
            for (int j = 0; j < 4; j++) W_out[64 * w + 16 * j + m] = wgt[j];
        }

        // ---- MFMA C-path (single fp16 from reused hA) + weighted agg ----
        f32x4_t ap = {0.f, 0.f, 0.f, 0.f};
#pragma unroll
        for (int j = 0; j < 4; j++) {
            const int row = 64 * w + 16 * j + m;
            const uint2_t rc2 = *(const uint2_t*)&hA[row * 10 + 2 * q];
            f32x4_t zz = {0.f, 0.f, 0.f, 0.f};
            const f32x4_t oc = __builtin_amdgcn_mfma_f32_16x16x16f16(
                ACf, __builtin_bit_cast(half4_t, rc2), zz, 0, 0, 0);
#pragma unroll
            for (int i = 0; i < 4; i++)
                ap[i] = fmaf(silu_f(oc[i] + b2cv[i]), wgt[j], ap[i]);
        }
#pragma unroll
        for (int off = 1; off <= 8; off <<= 1) {
            ap[0] += __shfl_xor(ap[0], off, 64);
            ap[1] += __shfl_xor(ap[1], off, 64);
            ap[2] += __shfl_xor(ap[2], off, 64);
            ap[3] += __shfl_xor(ap[3], off, 64);
        }
        if (m == 0)
            *(float4*)&aggw[ti & 1][w][4 * q] = make_float4(ap[0], ap[1], ap[2], ap[3]);
        pend = t; pendpar = ti & 1;
    }
    if (pend >= 0) {
        __syncthreads();
        if (tid < 16)
            agg_ws[((size_t)b * Tn + pend) * 16 + tid] =
                aggw[pendpar][0][tid] + aggw[pendpar][1][tid] +
                aggw[pendpar][2][tid] + aggw[pendpar][3][tid];
    }
}

// ---------- C2: merged matvec (MFMA, 16t x 256r) + LN finish, raw stays in LDS ----------
__global__ __launch_bounds__(256) void matvec_ln_kernel(
    const float* __restrict__ Wg, const float* __restrict__ V,
    const float* __restrict__ agg_ws, const int* __restrict__ len_ws,
    const float* __restrict__ lin_e_w, const float* __restrict__ lin_e_b,
    const float* __restrict__ ln_o_g, const float* __restrict__ ln_o_b,
    float* __restrict__ out)
{
    const int t0 = blockIdx.x * 16, b = blockIdx.y, tid = threadIdx.x;
    const int lane = tid & 63, w = tid >> 6, q = lane >> 4, m = lane & 15;
    const int len = len_ws[b];

    __shared__ __align__(16) float Wl[16 * 256];   // 16 KiB, XOR-swizzled float4 slots
    __shared__ __align__(16) float raw[16 * 260];  // 16.25 KiB

    // stage W tile: row = t-local, swizzle float4-slot ^= (row&7)
    const float4* Wg4 = (const float4*)Wg;
#pragma unroll
    for (int ch = 0; ch < 4; ch++) {
        const int idx = ch * 256 + tid;
        const int row = idx >> 6, sl = idx & 63;
        const int t = t0 + row;
        const float4 v = (t < Tn) ? Wg4[((size_t)b * Tn + t) * 64 + sl]
                                  : make_float4(0.f, 0.f, 0.f, 0.f);
        *(float4*)&Wl[row * 256 + ((sl ^ (row & 7)) << 2)] = v;
    }
    __syncthreads();

    // matvec: verified r9 phase (A row = m (t-local), B from V coalesced)
    f32x4_t acc[4];
#pragma unroll
    for (int i = 0; i < 4; i++) acc[i] = f32x4_t{0.f, 0.f, 0.f, 0.f};
    const float* Vb = V + (size_t)b * Kn * Rn;

#pragma unroll
    for (int ks = 0; ks < 16; ks++) {
        const float4 wv = *(const float4*)&Wl[m * 256 + (((4 * ks + q) ^ (m & 7)) << 2)];
        half4_t Ahi, Alo;
        split4(wv.x, wv.y, wv.z, wv.w, Ahi, Alo);
        const float* vp = Vb + (size_t)(ks * 16 + 4 * q) * Rn;
#pragma unroll
        for (int rt = 0; rt < 4; rt++) {
            const int rcol = w * 64 + rt * 16 + m;
            const float b0 = vp[rcol],          b1 = vp[Rn + rcol];
            const float b2 = vp[2 * Rn + rcol], b3 = vp[3 * Rn + rcol];
            half4_t Bh, Bl;
            split4(b0, b1, b2, b3, Bh, Bl);
            acc[rt] = __builtin_amdgcn_mfma_f32_16x16x16f16(Alo, Bh, acc[rt], 0, 0, 0);
            acc[rt] = __builtin_amdgcn_mfma_f32_16x16x16f16(Ahi, Bl, acc[rt], 0, 0, 0);
            acc[rt] = __builtin_amdgcn_mfma_f32_16x16x16f16(Ahi, Bh, acc[rt], 0, 0, 0);
        }
    }
#pragma unroll
    for (int rt = 0; rt < 4; rt++) {
#pragma unroll
        for (int i = 0; i < 4; i++)
            raw[(4 * q + i) * 260 + w * 64 + rt * 16 + m] = acc[rt][i];
    }
    __syncthreads();

    // LN phase: wave w handles t_local 4w..4w+3
#pragma unroll
    for (int j = 0; j < 4; j++) {
        const int tl = 4 * w + j;
        const int t = t0 + tl;
        if (t >= Tn) continue;
        float* __restrict__ row = out + ((size_t)b * Tn + t) * Rn;
        const int r0 = lane * 4;
        if (t >= len) {
            *(float4*)(row + r0) = make_float4(0.f, 0.f, 0.f, 0.f);
            continue;
        }
        float4 a4 = *(const float4*)&raw[tl * 260 + r0];
        {
            const float4 be = *(const float4*)(lin_e_b + r0);
            a4.x += be.x; a4.y += be.y; a4.z += be.z; a4.w += be.w;
        }
        const float* aggp = agg_ws + ((size_t)b * Tn + t) * 16;
#pragma unroll
        for (int p = 0; p < 16; p++) {
            const float a = aggp[p];
            const float4 l = *(const float4*)(lin_e_w + p * Rn + r0);
            a4.x = fmaf(a, l.x, a4.x); a4.y = fmaf(a, l.y, a4.y);
            a4.z = fmaf(a, l.z, a4.z); a4.w = fmaf(a, l.w, a4.w);
        }
        float s = (a4.x + a4.y) + (a4.z + a4.w);
#pragma unroll
        for (int off = 1; off <= 32; off <<= 1) s += __shfl_xor(s, off, 64);
        const float mu = s * (1.f / Rn);
        const float d0 = a4.x - mu, d1 = a4.y - mu, d2 = a4.z - mu, d3 = a4.w - mu;
        float vr = d0 * d0 + d1 * d1 + d2 * d2 + d3 * d3;
#pragma unroll
        for (int off = 1; off <= 32; off <<= 1) vr += __shfl_xor(vr, off, 64);
        const float rs = rsqrtf(vr * (1.f / Rn) + 1e-5f);
        const float4 g = *(const float4*)(ln_o_g + r0);
        const float4 bb = *(const float4*)(ln_o_b + r0);
        float4 res;
        res.x = d0 * rs * g.x + bb.x;
        res.y = d1 * rs * g.y + bb.y;
        res.z = d2 * rs * g.z + bb.z;
        res.w = d3 * rs * g.w + bb.w;
        *(float4*)(row + r0) = res;
    }
}

// ---------------- launch ----------------
extern "C" void kernel_launch(void* const* d_in, const int* in_sizes, int n_in,
                              void* d_out, int out_size, void* d_ws, size_t ws_size,
                              hipStream_t stream)
{
    const float* dur       = (const float*)d_in[0];
    const float* V         = (const float*)d_in[1];
    const unsigned char* text_mask = (const unsigned char*)d_in[3];
    const float* conv_c_w  = (const float*)d_in[4];
    const float* conv_c_b  = (const float*)d_in[5];
    const float* bn_c_g    = (const float*)d_in[6];
    const float* bn_c_b    = (const float*)d_in[7];
    const float* ln_c_g    = (const float*)d_in[8];
    const float* ln_c_b    = (const float*)d_in[9];
    const float* conv_w_w  = (const float*)d_in[10];
    const float* conv_w_b  = (const float*)d_in[11];
    const float* bn_w_g    = (const float*)d_in[12];
    const float* bn_w_b    = (const float*)d_in[13];
    const float* ln_w_g    = (const float*)d_in[14];
    const float* ln_w_b    = (const float*)d_in[15];
    const float* swc_w1    = (const float*)d_in[16];
    const float* swc_b1    = (const float*)d_in[17];
    const float* swc_w2    = (const float*)d_in[18];
    const float* swc_b2    = (const float*)d_in[19];
    const float* sww_w1    = (const float*)d_in[20];
    const float* sww_b1    = (const float*)d_in[21];
    const float* sww_w2    = (const float*)d_in[22];
    const float* sww_b2    = (const float*)d_in[23];
    const float* proj_w_w  = (const float*)d_in[24];
    const float* proj_w_b  = (const float*)d_in[25];
    const float* lin_e_w   = (const float*)d_in[26];
    const float* lin_e_b   = (const float*)d_in[27];
    const float* ln_o_g    = (const float*)d_in[28];
    const float* ln_o_b    = (const float*)d_in[29];

    float* out = (float*)d_out;
    float* wsf = (float*)d_ws;
    int*   len_ws   = (int*)wsf;                // 16 (pad 64)
    float* alpha_ws = wsf + 64;                 // 32 (pad 64)
    float* ab_ws    = wsf + 128;                // 16*256*32 = 131072
    float* scratch  = ab_ws + 131072;           // part 524288, then aliased agg 256000
    float* part     = scratch;
    float* agg_ws   = scratch;

    conv_partial_kernel<<<dim3(8, Bn), dim3(256), 0, stream>>>(V, conv_w_w, conv_c_w, part);
    conv_scan_finish_kernel<<<dim3(Bn), dim3(256), 0, stream>>>(
        dur, part, text_mask,
        conv_w_b, bn_w_g, bn_w_b, ln_w_g, ln_w_b,
        conv_c_b, bn_c_g, bn_c_b, ln_c_g, ln_c_b,
        sww_w1, sww_b1, swc_w1, swc_b1,
        alpha_ws, ab_ws, len_ws, out);
    logits_kernel<<<dim3(Tn / 8, Bn), dim3(256), 0, stream>>>(
        text_mask, len_ws, alpha_ws, ab_ws,
        sww_w2, sww_b2, proj_w_w, proj_w_b,
        swc_w2, swc_b2,
        agg_ws, out);
    matvec_ln_kernel<<<dim3((Tn + 15) / 16, Bn), dim3(256), 0, stream>>>(
        out + W_OFF, V, agg_ws, len_ws,
        lin_e_w, lin_e_b, ln_o_g, ln_o_b, out);
}

// Round 13
// 157.606 us; speedup vs baseline: 2.2648x; 1.0151x over previous
//
#include <hip/hip_runtime.h>
#include <cstddef>

constexpr int Bn = 16, Kn = 256, Rn = 256, Tn = 1000, C8 = 8, SW = 16;
constexpr size_t UP_SZ    = (size_t)Bn * Tn * Rn;          // 4,096,000
constexpr size_t MASK_OFF = UP_SZ;                          // + 16,000
constexpr size_t LEN_OFF  = MASK_OFF + (size_t)Bn * Tn;     // + 16
constexpr size_t W_OFF    = LEN_OFF + Bn;                    // + 4,096,000

using half4_t = __attribute__((ext_vector_type(4))) _Float16;
using f32x4_t = __attribute__((ext_vector_type(4))) float;
using uint2_t = __attribute__((ext_vector_type(2))) unsigned int;

__device__ __forceinline__ float fast_rcp(float x) { return __builtin_amdgcn_rcpf(x); }
__device__ __forceinline__ float fast_exp2(float x) { return __builtin_amdgcn_exp2f(x); }
constexpr float LOG2E = 1.44269504088896340736f;
__device__ __forceinline__ float silu_f(float x) {
    return x * fast_rcp(1.f + fast_exp2(-LOG2E * x));
}

// pack 4 floats -> fp16 hi + lo halves
__device__ __forceinline__ void split4(const float x0, const float x1,
                                       const float x2, const float x3,
                                       half4_t& hi, half4_t& lo)
{
    const auto h01 = __builtin_amdgcn_cvt_pkrtz(x0, x1);
    const auto h23 = __builtin_amdgcn_cvt_pkrtz(x2, x3);
    uint2_t uh; uh.x = __builtin_bit_cast(unsigned int, h01);
    uh.y = __builtin_bit_cast(unsigned int, h23);
    hi = __builtin_bit_cast(half4_t, uh);
    const auto l01 = __builtin_amdgcn_cvt_pkrtz(x0 - (float)h01.x, x1 - (float)h01.y);
    const auto l23 = __builtin_amdgcn_cvt_pkrtz(x2 - (float)h23.x, x3 - (float)h23.y);
    uint2_t ul; ul.x = __builtin_bit_cast(unsigned int, l01);
    ul.y = __builtin_bit_cast(unsigned int, l23);
    lo = __builtin_bit_cast(half4_t, ul);
}

// ---------------- conv phase A: partial sums over r-chunks ----------------
__global__ __launch_bounds__(256) void conv_partial_kernel(
    const float* __restrict__ V,
    const float* __restrict__ wW, const float* __restrict__ wC,
    float* __restrict__ part)
{
    const int rc = blockIdx.x, b = blockIdx.y, k = threadIdx.x;
    constexpr int RPAD = 33;
    __shared__ float vt[258 * RPAD];
    if (k < 16) {
        const int row = (k < 8) ? 0 : 257;
        const int j = (k & 7) * 4;
        vt[row * RPAD + j] = 0.f; vt[row * RPAD + j + 1] = 0.f;
        vt[row * RPAD + j + 2] = 0.f; vt[row * RPAD + j + 3] = 0.f;
    }
    const float* vsrc = V + ((size_t)(b * Kn + k)) * Rn + rc * 32;
#pragma unroll
    for (int j = 0; j < 8; j++) {
        const float4 qv = *(const float4*)(vsrc + j * 4);
        float* dst = &vt[(k + 1) * RPAD + j * 4];
        dst[0] = qv.x; dst[1] = qv.y; dst[2] = qv.z; dst[3] = qv.w;
    }
    __syncthreads();

    float aw[C8], ac[C8];
#pragma unroll
    for (int c = 0; c < C8; c++) { aw[c] = 0.f; ac[c] = 0.f; }
    for (int dk = 0; dk < 3; dk++) {
        const float* wp = wW + (size_t)(dk * Rn + rc * 32) * C8;
        const float* cp = wC + (size_t)(dk * Rn + rc * 32) * C8;
        const float* vrow = &vt[(k + dk) * RPAD];
#pragma unroll 4
        for (int r = 0; r < 32; r++) {
            const float v = vrow[r];
#pragma unroll
            for (int c = 0; c < C8; c++) {
                aw[c] = fmaf(v, wp[r * C8 + c], aw[c]);
                ac[c] = fmaf(v, cp[r * C8 + c], ac[c]);
            }
        }
    }
    float* dst = part + ((size_t)(b * 8 + rc) * Kn + k) * 16;
    *(float4*)(dst + 0)  = make_float4(aw[0], aw[1], aw[2], aw[3]);
    *(float4*)(dst + 4)  = make_float4(aw[4], aw[5], aw[6], aw[7]);
    *(float4*)(dst + 8)  = make_float4(ac[0], ac[1], ac[2], ac[3]);
    *(float4*)(dst + 12) = make_float4(ac[4], ac[5], ac[6], ac[7]);
}

// ---------------- conv phase B (fused with scan): reduce + post + beta/alpha ----------------
__device__ __forceinline__ void conv_post(
    const float* acc, const float* cb, const float* bng, const float* bnb,
    const float* lng, const float* lnb, const float* w1, const float* b1,
    float* __restrict__ dst)
{
    const float bnscale = rsqrtf(1.f + 1e-5f);
    float x[C8];
    float mu = 0.f;
#pragma unroll
    for (int c = 0; c < C8; c++) {
        float v = (acc[c] + cb[c]) * (bng[c] * bnscale) + bnb[c];
        v = silu_f(v);
        x[c] = v; mu += v;
    }
    mu *= (1.f / C8);
    float var = 0.f;
#pragma unroll
    for (int c = 0; c < C8; c++) { float dd = x[c] - mu; var += dd * dd; }
    var *= (1.f / C8);
    const float rs = rsqrtf(var + 1e-5f);
    float y[C8];
#pragma unroll
    for (int c = 0; c < C8; c++) y[c] = (x[c] - mu) * rs * lng[c] + lnb[c];
#pragma unroll
    for (int c2 = 0; c2 < SW; c2++) {
        float a = b1[c2];
#pragma unroll
        for (int p = 0; p < C8; p++) a = fmaf(y[p], w1[(2 + p) * SW + c2], a);
        dst[c2] = a;
    }
}

__global__ __launch_bounds__(256) void conv_scan_finish_kernel(
    const float* __restrict__ dur,
    const float* __restrict__ part,
    const unsigned char* __restrict__ tmask_g,
    const float* __restrict__ bW, const float* __restrict__ bngW, const float* __restrict__ bnbW,
    const float* __restrict__ lngW, const float* __restrict__ lnbW,
    const float* __restrict__ bC, const float* __restrict__ bngC, const float* __restrict__ bnbC,
    const float* __restrict__ lngC, const float* __restrict__ lnbC,
    const float* __restrict__ sww_w1, const float* __restrict__ sww_b1,
    const float* __restrict__ swc_w1, const float* __restrict__ swc_b1,
    float* __restrict__ alpha_ws, float* __restrict__ ab_ws,
    int* __restrict__ len_ws, float* __restrict__ out)
{
    const int b = blockIdx.x, k = threadIdx.x;
    __shared__ float sc[Kn];
    const float d = dur[b * Kn + k];
    sc[k] = d;
    __syncthreads();
    for (int off = 1; off < Kn; off <<= 1) {
        float v = (k >= off) ? sc[k - off] : 0.f;
        __syncthreads();
        sc[k] += v;
        __syncthreads();
    }
    const float ek = sc[k];
    const float sk = ek - d;
    const float total = sc[Kn - 1];
    int len = (int)rintf(total);
    if (len > Tn) len = Tn;
    if (k == 0) { len_ws[b] = len; out[LEN_OFF + b] = (float)len; }
    for (int t = k; t < Tn; t += 256)
        out[MASK_OFF + (size_t)b * Tn + t] = (t >= len) ? 1.f : 0.f;
    if (b == 0 && k < 16) {
        alpha_ws[k]      = sww_w1[k] - sww_w1[SW + k];
        alpha_ws[16 + k] = swc_w1[k] - swc_w1[SW + k];
    }

    float aw[C8], ac[C8];
#pragma unroll
    for (int c = 0; c < C8; c++) { aw[c] = 0.f; ac[c] = 0.f; }
#pragma unroll 2
    for (int rc = 0; rc < 8; rc++) {
        const float4* p = (const float4*)(part + ((size_t)(b * 8 + rc) * Kn + k) * 16);
        const float4 q0 = p[0], q1 = p[1], q2 = p[2], q3 = p[3];
        aw[0] += q0.x; aw[1] += q0.y; aw[2] += q0.z; aw[3] += q0.w;
        aw[4] += q1.x; aw[5] += q1.y; aw[6] += q1.z; aw[7] += q1.w;
        ac[0] += q2.x; ac[1] += q2.y; ac[2] += q2.z; ac[3] += q2.w;
        ac[4] += q3.x; ac[5] += q3.y; ac[6] += q3.z; ac[7] += q3.w;
    }
    float basew[SW], basec[SW];
    conv_post(aw, bW, bngW, bnbW, lngW, lnbW, sww_w1, sww_b1, basew);
    conv_post(ac, bC, bngC, bnbC, lngC, lnbC, swc_w1, swc_b1, basec);

    const bool msk = tmask_g[b * Kn + k] != 0;
    float* dst = ab_ws + ((size_t)(b * Kn) + k) * 32;
#pragma unroll
    for (int c = 0; c < SW; c++) {
        const float w0w = sww_w1[c], w1w_ = sww_w1[SW + c];
        const float w0c = swc_w1[c], w1c_ = swc_w1[SW + c];
        dst[c]      = msk ? basew[c] : fmaf(ek, w1w_, fmaf(-sk, w0w, basew[c]));
        dst[16 + c] = msk ? basec[c] : fmaf(ek, w1c_, fmaf(-sk, w0c, basec[c]));
    }
}

// ---------------- C1: swish blocks via MFMA + softmax + W + agg (4 t/block) ----------------
// hC eliminated (C-path reuses hA after W reads, wave-local rows).
// Single barrier per t: waves publish (max_w, sum_w) pre-barrier; combined after.
// red[] and aggw[] parity-double-buffered to remove the second barrier's hazard.
__global__ __launch_bounds__(256) void logits_kernel(
    const unsigned char* __restrict__ tm, const int* __restrict__ len_ws,
    const float* __restrict__ alpha_ws, const float* __restrict__ ab_ws,
    const float* __restrict__ sww_w2, const float* __restrict__ sww_b2,
    const float* __restrict__ proj_w, const float* __restrict__ proj_b,
    const float* __restrict__ swc_w2, const float* __restrict__ swc_b2,
    float* __restrict__ agg_ws, float* __restrict__ out)
{
    const int t0 = blockIdx.x * 4, b = blockIdx.y, tid = threadIdx.x;
    const int lane = tid & 63, w = tid >> 6, q = lane >> 4, m = lane & 15;
    const int len = len_ws[b];

    __shared__ __align__(16) unsigned int hA[256 * 10];  // h_w hi, then reused for h_c
    __shared__ __align__(16) unsigned int hB[256 * 10];  // h_w lo
    __shared__ float red[2][8];
    __shared__ __align__(16) float aggw[2][4][16];

    // per-thread beta vectors (alpha is uniform -> SGPRs via alpha_ws[const])
    float bw[16], bc[16];
    {
        const float4* bp = (const float4*)(ab_ws + (((size_t)b * Kn) + tid) * 32);
#pragma unroll
        for (int i = 0; i < 4; i++) {
            const float4 v = bp[i];
            bw[4*i] = v.x; bw[4*i+1] = v.y; bw[4*i+2] = v.z; bw[4*i+3] = v.w;
        }
#pragma unroll
        for (int i = 0; i < 4; i++) {
            const float4 v = bp[4 + i];
            bc[4*i] = v.x; bc[4*i+1] = v.y; bc[4*i+2] = v.z; bc[4*i+3] = v.w;
        }
    }
    const float mk = (tm[b * Kn + tid] != 0) ? 0.f : 1.f;

    // A-fragments (identical pattern to verified r5 kernel)
    half4_t AWhi, AWlo, ACf;
    float pj[4], b2wv[4], b2cv[4], mb[4];
#pragma unroll
    for (int i = 0; i < 4; i++) {
        const int c = 4 * q + i;
        const float vw = sww_w2[c * SW + m];
        const _Float16 hi = (_Float16)vw;
        AWhi[i] = hi;
        AWlo[i] = (_Float16)(vw - (float)hi);
        ACf[i]  = (_Float16)(swc_w2[c * SW + m]);
        pj[i]   = proj_w[c];
        b2wv[i] = sww_b2[c];
        b2cv[i] = swc_b2[c];
        mb[i]   = (tm[b * Kn + 64 * w + 16 * i + m] != 0) ? -INFINITY : 0.f;
    }
    const float pb = proj_b[0];

    int pend = -1, pendpar = 0;

    for (int ti = 0; ti < 4; ti++) {
        const int t = t0 + ti;
        float* __restrict__ W_out = out + W_OFF + ((size_t)b * Tn + t) * Kn;
        if (t >= len) { W_out[tid] = 0.f; continue; }   // uniform over block
        const float u = (float)(t + 1);
        const float umk = u * mk;
        const int par = ti & 1;

        // ---- W-path layer-1: arg = umk*alpha[c] + beta[k][c]; silu; fp16 pack ----
#pragma unroll
        for (int p = 0; p < 8; p++) {
            const float x0 = fmaf(umk, alpha_ws[2*p],   bw[2*p]);
            const float x1 = fmaf(umk, alpha_ws[2*p+1], bw[2*p+1]);
            const float h0 = silu_f(x0), h1 = silu_f(x1);
            const auto hp = __builtin_amdgcn_cvt_pkrtz(h0, h1);
            hA[tid * 10 + p] = __builtin_bit_cast(unsigned int, hp);
            const float l0 = h0 - (float)hp.x, l1 = h1 - (float)hp.y;
            hB[tid * 10 + p] = __builtin_bit_cast(unsigned int,
                                __builtin_amdgcn_cvt_pkrtz(l0, l1));
        }
        // wave-local rows: in-wave DS ordering suffices (no barrier needed)

        // ---- MFMA W-path: split-fp16, 3 mfma per 16x16 tile ----
        f32x4_t o[4];
#pragma unroll
        for (int j = 0; j < 4; j++) {
            const int row = 64 * w + 16 * j + m;
            const uint2_t rh = *(const uint2_t*)&hA[row * 10 + 2 * q];
            const uint2_t rl = *(const uint2_t*)&hB[row * 10 + 2 * q];
            const half4_t bh = __builtin_bit_cast(half4_t, rh);
            const half4_t bl = __builtin_bit_cast(half4_t, rl);
            f32x4_t acc = {0.f, 0.f, 0.f, 0.f};
            acc = __builtin_amdgcn_mfma_f32_16x16x16f16(AWlo, bh, acc, 0, 0, 0);
            acc = __builtin_amdgcn_mfma_f32_16x16x16f16(AWhi, bl, acc, 0, 0, 0);
            acc = __builtin_amdgcn_mfma_f32_16x16x16f16(AWhi, bh, acc, 0, 0, 0);
            o[j] = acc;
        }

        // ---- C-path layer-1 (AFTER W reads): reuse hA, wave-local ----
#pragma unroll
        for (int p = 0; p < 8; p++) {
            const float y0 = fmaf(umk, alpha_ws[16 + 2*p],   bc[2*p]);
            const float y1 = fmaf(umk, alpha_ws[16 + 2*p+1], bc[2*p+1]);
            hA[tid * 10 + p] = __builtin_bit_cast(unsigned int,
                                __builtin_amdgcn_cvt_pkrtz(silu_f(y0), silu_f(y1)));
        }

        // ---- logit: silu(o + b2) . proj, reduce over c2 ----
        float lg[4];
#pragma unroll
        for (int j = 0; j < 4; j++) {
            float s = silu_f(o[j][0] + b2wv[0]) * pj[0];
            s = fmaf(silu_f(o[j][1] + b2wv[1]), pj[1], s);
            s = fmaf(silu_f(o[j][2] + b2wv[2]), pj[2], s);
            s = fmaf(silu_f(o[j][3] + b2wv[3]), pj[3], s);
            s += __shfl_xor(s, 16, 64);
            s += __shfl_xor(s, 32, 64);
            lg[j] = s + pb + mb[j];
        }

        // ---- softmax: per-wave max + sum, ONE barrier, combine ----
        float mx = fmaxf(fmaxf(lg[0], lg[1]), fmaxf(lg[2], lg[3]));
#pragma unroll
        for (int off = 1; off <= 8; off <<= 1) mx = fmaxf(mx, __shfl_xor(mx, off, 64));
        float pex[4];
        float sw = 0.f;
#pragma unroll
        for (int j = 0; j < 4; j++) {
            pex[j] = fast_exp2(LOG2E * (lg[j] - mx));
            sw += pex[j];
        }
#pragma unroll
        for (int off = 1; off <= 8; off <<= 1) sw += __shfl_xor(sw, off, 64);
        if (lane == 0) { red[par][w] = mx; red[par][4 + w] = sw; }
        __syncthreads();                        // S: the only barrier per t
        if (pend >= 0) {                        // deferred agg finalize for t-1
            if (tid < 16)
                agg_ws[((size_t)b * Tn + pend) * 16 + tid] =
                    aggw[pendpar][0][tid] + aggw[pendpar][1][tid] +
                    aggw[pendpar][2][tid] + aggw[pendpar][3][tid];
            pend = -1;
        }
        const float M = fmaxf(fmaxf(red[par][0], red[par][1]),
                              fmaxf(red[par][2], red[par][3]));
        float total = 0.f;
#pragma unroll
        for (int ww = 0; ww < 4; ww++)
            total = fmaf(red[par][4 + ww],
                         fast_exp2(LOG2E * (red[par][ww] - M)), total);
        const float corr = fast_exp2(LOG2E * (mx - M)) * fast_rcp(total);
        float wgt[4];
#pragma unroll
        for (int j = 0; j < 4; j++) wgt[j] = pex[j] * corr;
        if (q == 0) {
#pragma unroll
            for (int j = 0; j < 4; j++) W_out[64 * w + 16 * j + m] = wgt[j];
        }

        // ---- MFMA C-path (single fp16 from reused hA) + weighted agg ----
        f32x4_t ap = {0.f, 0.f, 0.f, 0.f};
#pragma unroll
        for (int j = 0; j < 4; j++) {
            const int row = 64 * w + 16 * j + m;
            const uint2_t rc2 = *(const uint2_t*)&hA[row * 10 + 2 * q];
            f32x4_t zz = {0.f, 0.f, 0.f, 0.f};
            const f32x4_t oc = __builtin_amdgcn_mfma_f32_16x16x16f16(
                ACf, __builtin_bit_cast(half4_t, rc2), zz, 0, 0, 0);
#pragma unroll
            for (int i = 0; i < 4; i++)
                ap[i] = fmaf(silu_f(oc[i] + b2cv[i]), wgt[j], ap[i]);
        }
#pragma unroll
        for (int off = 1; off <= 8; off <<= 1) {
            ap[0] += __shfl_xor(ap[0], off, 64);
            ap[1] += __shfl_xor(ap[1], off, 64);
            ap[2] += __shfl_xor(ap[2], off, 64);
            ap[3] += __shfl_xor(ap[3], off, 64);
        }
        if (m == 0)
            *(float4*)&aggw[par][w][4 * q] = make_float4(ap[0], ap[1], ap[2], ap[3]);
        pend = t; pendpar = par;
    }
    if (pend >= 0) {
        __syncthreads();
        if (tid < 16)
            agg_ws[((size_t)b * Tn + pend) * 16 + tid] =
                aggw[pendpar][0][tid] + aggw[pendpar][1][tid] +
                aggw[pendpar][2][tid] + aggw[pendpar][3][tid];
    }
}

// ---------- C2: merged matvec (MFMA, 16t x 256r) + LN finish, raw stays in LDS ----------
__global__ __launch_bounds__(256) void matvec_ln_kernel(
    const float* __restrict__ Wg, const float* __restrict__ V,
    const float* __restrict__ agg_ws, const int* __restrict__ len_ws,
    const float* __restrict__ lin_e_w, const float* __restrict__ lin_e_b,
    const float* __restrict__ ln_o_g, const float* __restrict__ ln_o_b,
    float* __restrict__ out)
{
    const int t0 = blockIdx.x * 16, b = blockIdx.y, tid = threadIdx.x;
    const int lane = tid & 63, w = tid >> 6, q = lane >> 4, m = lane & 15;
    const int len = len_ws[b];

    __shared__ __align__(16) float Wl[16 * 256];   // 16 KiB, XOR-swizzled float4 slots
    __shared__ __align__(16) float raw[16 * 260];  // 16.25 KiB

    // stage W tile: row = t-local, swizzle float4-slot ^= (row&7)
    const float4* Wg4 = (const float4*)Wg;
#pragma unroll
    for (int ch = 0; ch < 4; ch++) {
        const int idx = ch * 256 + tid;
        const int row = idx >> 6, sl = idx & 63;
        const int t = t0 + row;
        const float4 v = (t < Tn) ? Wg4[((size_t)b * Tn + t) * 64 + sl]
                                  : make_float4(0.f, 0.f, 0.f, 0.f);
        *(float4*)&Wl[row * 256 + ((sl ^ (row & 7)) << 2)] = v;
    }
    __syncthreads();

    // matvec: verified r9 phase (A row = m (t-local), B from V coalesced)
    f32x4_t acc[4];
#pragma unroll
    for (int i = 0; i < 4; i++) acc[i] = f32x4_t{0.f, 0.f, 0.f, 0.f};
    const float* Vb = V + (size_t)b * Kn * Rn;

#pragma unroll
    for (int ks = 0; ks < 16; ks++) {
        const float4 wv = *(const float4*)&Wl[m * 256 + (((4 * ks + q) ^ (m & 7)) << 2)];
        half4_t Ahi, Alo;
        split4(wv.x, wv.y, wv.z, wv.w, Ahi, Alo);
        const float* vp = Vb + (size_t)(ks * 16 + 4 * q) * Rn;
#pragma unroll
        for (int rt = 0; rt < 4; rt++) {
            const int rcol = w * 64 + rt * 16 + m;
            const float b0 = vp[rcol],          b1 = vp[Rn + rcol];
            const float b2 = vp[2 * Rn + rcol], b3 = vp[3 * Rn + rcol];
            half4_t Bh, Bl;
            split4(b0, b1, b2, b3, Bh, Bl);
            acc[rt] = __builtin_amdgcn_mfma_f32_16x16x16f16(Alo, Bh, acc[rt], 0, 0, 0);
            acc[rt] = __builtin_amdgcn_mfma_f32_16x16x16f16(Ahi, Bl, acc[rt], 0, 0, 0);
            acc[rt] = __builtin_amdgcn_mfma_f32_16x16x16f16(Ahi, Bh, acc[rt], 0, 0, 0);
        }
    }
#pragma unroll
    for (int rt = 0; rt < 4; rt++) {
#pragma unroll
        for (int i = 0; i < 4; i++)
            raw[(4 * q + i) * 260 + w * 64 + rt * 16 + m] = acc[rt][i];
    }
    __syncthreads();

    // LN phase: wave w handles t_local 4w..4w+3
#pragma unroll
    for (int j = 0; j < 4; j++) {
        const int tl = 4 * w + j;
        const int t = t0 + tl;
        if (t >= Tn) continue;
        float* __restrict__ row = out + ((size_t)b * Tn + t) * Rn;
        const int r0 = lane * 4;
        if (t >= len) {
            *(float4*)(row + r0) = make_float4(0.f, 0.f, 0.f, 0.f);
            continue;
        }
        float4 a4 = *(const float4*)&raw[tl * 260 + r0];
        {
            const float4 be = *(const float4*)(lin_e_b + r0);
            a4.x += be.x; a4.y += be.y; a4.z += be.z; a4.w += be.w;
        }
        const float* aggp = agg_ws + ((size_t)b * Tn + t) * 16;
#pragma unroll
        for (int p = 0; p < 16; p++) {
            const float a = aggp[p];
            const float4 l = *(const float4*)(lin_e_w + p * Rn + r0);
            a4.x = fmaf(a, l.x, a4.x); a4.y = fmaf(a, l.y, a4.y);
            a4.z = fmaf(a, l.z, a4.z); a4.w = fmaf(a, l.w, a4.w);
        }
        float s = (a4.x + a4.y) + (a4.z + a4.w);
#pragma unroll
        for (int off = 1; off <= 32; off <<= 1) s += __shfl_xor(s, off, 64);
        const float mu = s * (1.f / Rn);
        const float d0 = a4.x - mu, d1 = a4.y - mu, d2 = a4.z - mu, d3 = a4.w - mu;
        float vr = d0 * d0 + d1 * d1 + d2 * d2 + d3 * d3;
#pragma unroll
        for (int off = 1; off <= 32; off <<= 1) vr += __shfl_xor(vr, off, 64);
        const float rs = rsqrtf(vr * (1.f / Rn) + 1e-5f);
        const float4 g = *(const float4*)(ln_o_g + r0);
        const float4 bb = *(const float4*)(ln_o_b + r0);
        float4 res;
        res.x = d0 * rs * g.x + bb.x;
        res.y = d1 * rs * g.y + bb.y;
        res.z = d2 * rs * g.z + bb.z;
        res.w = d3 * rs * g.w + bb.w;
        *(float4*)(row + r0) = res;
    }
}

// ---------------- launch ----------------
extern "C" void kernel_launch(void* const* d_in, const int* in_sizes, int n_in,
                              void* d_out, int out_size, void* d_ws, size_t ws_size,
                              hipStream_t stream)
{
    const float* dur       = (const float*)d_in[0];
    const float* V         = (const float*)d_in[1];
    const unsigned char* text_mask = (const unsigned char*)d_in[3];
    const float* conv_c_w  = (const float*)d_in[4];
    const float* conv_c_b  = (const float*)d_in[5];
    const float* bn_c_g    = (const float*)d_in[6];
    const float* bn_c_b    = (const float*)d_in[7];
    const float* ln_c_g    = (const float*)d_in[8];
    const float* ln_c_b    = (const float*)d_in[9];
    const float* conv_w_w  = (const float*)d_in[10];
    const float* conv_w_b  = (const float*)d_in[11];
    const float* bn_w_g    = (const float*)d_in[12];
    const float* bn_w_b    = (const float*)d_in[13];
    const float* ln_w_g    = (const float*)d_in[14];
    const float* ln_w_b    = (const float*)d_in[15];
    const float* swc_w1    = (const float*)d_in[16];
    const float* swc_b1    = (const float*)d_in[17];
    const float* swc_w2    = (const float*)d_in[18];
    const float* swc_b2    = (const float*)d_in[19];
    const float* sww_w1    = (const float*)d_in[20];
    const float* sww_b1    = (const float*)d_in[21];
    const float* sww_w2    = (const float*)d_in[22];
    const float* sww_b2    = (const float*)d_in[23];
    const float* proj_w_w  = (const float*)d_in[24];
    const float* proj_w_b  = (const float*)d_in[25];
    const float* lin_e_w   = (const float*)d_in[26];
    const float* lin_e_b   = (const float*)d_in[27];
    const float* ln_o_g    = (const float*)d_in[28];
    const float* ln_o_b    = (const float*)d_in[29];

    float* out = (float*)d_out;
    float* wsf = (float*)d_ws;
    int*   len_ws   = (int*)wsf;                // 16 (pad 64)
    float* alpha_ws = wsf + 64;                 // 32 (pad 64)
    float* ab_ws    = wsf + 128;                // 16*256*32 = 131072
    float* scratch  = ab_ws + 131072;           // part 524288, then aliased agg 256000
    float* part     = scratch;
    float* agg_ws   = scratch;

    conv_partial_kernel<<<dim3(8, Bn), dim3(256), 0, stream>>>(V, conv_w_w, conv_c_w, part);
    conv_scan_finish_kernel<<<dim3(Bn), dim3(256), 0, stream>>>(
        dur, part, text_mask,
        conv_w_b, bn_w_g, bn_w_b, ln_w_g, ln_w_b,
        conv_c_b, bn_c_g, bn_c_b, ln_c_g, ln_c_b,
        sww_w1, sww_b1, swc_w1, swc_b1,
        alpha_ws, ab_ws, len_ws, out);
    logits_kernel<<<dim3(Tn / 4, Bn), dim3(256), 0, stream>>>(
        text_mask, len_ws, alpha_ws, ab_ws,
        sww_w2, sww_b2, proj_w_w, proj_w_b,
        swc_w2, swc_b2,
        agg_ws, out);
    matvec_ln_kernel<<<dim3((Tn + 15) / 16, Bn), dim3(256), 0, stream>>>(
        out + W_OFF, V, agg_ws, len_ws,
        lin_e_w, lin_e_b, ln_o_g, ln_o_b, out);
}